// Round 4
// baseline (219.501 us; speedup 1.0000x reference)
//
#include <hip/hip_runtime.h>
#include <hip/hip_bf16.h>

// Problem constants
#define B_DIM 1024
#define L_DIM 32
#define K_DIM 8
#define G_DIM 8
#define C_DIM 128
#define S_DIM 32
#define DIN   104   // 2L + K + S

typedef __bf16  bf16x8 __attribute__((ext_vector_type(8)));
typedef float   f32x4  __attribute__((ext_vector_type(4)));

union frag_u { uint4 u; bf16x8 v; };

static __device__ __forceinline__ unsigned short f2b(float f) {
    union { float f; unsigned int i; } v; v.f = f;
    unsigned int x = v.i;
    return (unsigned short)((x + 0x7FFFu + ((x >> 16) & 1u)) >> 16);  // RNE
}
static __device__ __forceinline__ unsigned int pk2(float a, float b) {
    return (unsigned int)f2b(a) | ((unsigned int)f2b(b) << 16);
}
static __device__ __forceinline__ bf16x8 ld_frag(const unsigned short* p) {
    frag_u t; t.u = *(const uint4*)p; return t.v;
}

// ---------------------------------------------------------------------------
// Kernel 1: decisions in fp64: cvar/tflag bytes, adjacency bits (wave ballot),
// zero the fp32 accumulator. One block per batch element.
// ---------------------------------------------------------------------------
__global__ __launch_bounds__(256) void prep_kernel(
    const float* __restrict__ u_gumbel,      // [B,L,K]
    const float* __restrict__ u_adj,         // [B,G,K,K]
    const float* __restrict__ target_params, // [L,K]
    const float* __restrict__ enco_theta,    // [K,K]
    const float* __restrict__ enco_gamma,    // [K,K]
    const int*   __restrict__ target,        // [B]
    float*       __restrict__ acc,           // [B]
    unsigned char* __restrict__ cvarpk,      // [B][32]  cvar | tflag<<3
    unsigned long long* __restrict__ adjbits)// [B][8]
{
    __shared__ double ep[64];
    const int t = threadIdx.x;
    const int b = blockIdx.x;
    if (t < 64) {
        double th = (double)enco_theta[t];
        double ga = (double)enco_gamma[t];
        ep[t] = (1.0 / (1.0 + exp(-th))) * (1.0 / (1.0 + exp(-ga)));
    }
    if (t == 0) acc[b] = 0.0f;
    __syncthreads();

    // gumbel argmax: thread t = l*8 + k; 8-lane subgroup reduction
    {
        const int l = t >> 3, k = t & 7;
        double u = (double)u_gumbel[b * 256 + t];
        double g = -log(-log(u + 1e-10) + 1e-10);
        double v = (double)target_params[t] + g;   // TAU = 1
        int bk = k;
        #pragma unroll
        for (int off = 1; off < 8; off <<= 1) {
            double ov = __shfl_xor(v, off, 64);
            int   obk = __shfl_xor(bk, off, 64);
            if (ov > v || (ov == v && obk < bk)) { v = ov; bk = obk; }
        }
        if (k == 0) {
            int tg = target[b];
            cvarpk[b * 32 + l] = (unsigned char)(bk | ((bk == tg) ? 8 : 0));
        }
    }
    // adjacency: wave w handles g = w and g = w+4; bit i (= k*8+l) from lane i
    {
        const int wv = t >> 6, lane = t & 63;
        #pragma unroll
        for (int q = 0; q < 2; ++q) {
            int gg = wv + 4 * q;
            double u = (double)u_adj[b * 512 + gg * 64 + lane];
            unsigned long long m = __ballot(u < ep[lane]);
            if (lane == 0) adjbits[b * 8 + gg] = m;
        }
    }
}

// ---------------------------------------------------------------------------
// Kernel 1b: convert W1/W2 fp32 -> bf16 into d_ws, in MFMA fragment order:
//   frag F = ((which*32 + l)*2 + wm)*16 + mt*4 + ks ; data = [lane][8]
//   element = W[l][ m = 16*(4*wm+mt) + (lane&15) ][ k = ks*32 + (lane>>4)*8 + j ]
//   (W1 zero-padded K: 104..127 -> 0)
// ---------------------------------------------------------------------------
__global__ __launch_bounds__(256) void wprep_kernel(
    const float* __restrict__ W1,    // [32][128][104]
    const float* __restrict__ W2,    // [32][128][128]
    unsigned short* __restrict__ wscr)
{
    int gtid  = blockIdx.x * 256 + threadIdx.x;   // [0, 131072)
    int lane  = gtid & 63;
    int ks    = (gtid >> 6) & 3;
    int mt    = (gtid >> 8) & 3;
    int wm    = (gtid >> 10) & 1;
    int l     = (gtid >> 11) & 31;
    int which = gtid >> 16;
    int m  = 16 * (4 * wm + mt) + (lane & 15);
    int k0 = ks * 32 + (lane >> 4) * 8;

    uint4 out;
    if (which == 0) {
        if (k0 >= 104) {
            out = make_uint4(0u, 0u, 0u, 0u);
        } else {
            const float* p = W1 + (size_t)l * 13312 + m * 104 + k0;
            float4 a = *(const float4*)p, bq = *(const float4*)(p + 4);
            out = make_uint4(pk2(a.x, a.y), pk2(a.z, a.w), pk2(bq.x, bq.y), pk2(bq.z, bq.w));
        }
    } else {
        const float* p = W2 + (size_t)l * 16384 + m * 128 + k0;
        float4 a = *(const float4*)p, bq = *(const float4*)(p + 4);
        out = make_uint4(pk2(a.x, a.y), pk2(a.z, a.w), pk2(bq.x, bq.y), pk2(bq.z, bq.w));
    }
    *(uint4*)(wscr + (size_t)gtid * 8) = out;   // gtid*8 == F*512 + lane*8
}

// ---------------------------------------------------------------------------
// Kernel 2: fused build-X + GEMM1 + GN1 + SiLU + GEMM2 + GN2 + SiLU + GEMM3 +
// tanh-scale + KLD + g-mean, atomicAdd into acc[b].
// Grid 512: l = blockIdx&31, grp = blockIdx>>5. 4 tiles of 128 rows; 4 waves
// tile D[c][row] 2x2. Weight fragments streamed from bf16 scratch PER ks
// (wfr[4] + one-step lookahead) to keep peak register demand ~160.
// launch_bounds(256,1): allocator must not spill to scratch.
// ---------------------------------------------------------------------------
__global__ __launch_bounds__(256, 1) void fused_kernel(
    const float* __restrict__ z_sample,   // [B,32]
    const float* __restrict__ z_mean,     // [B,32]
    const float* __restrict__ z_logstd,   // [B,32]
    const float* __restrict__ z_shared,   // [B,32]
    const float* __restrict__ pb1,        // [32][128]
    const float* __restrict__ g1w,
    const float* __restrict__ g1b,
    const float* __restrict__ pb2,
    const float* __restrict__ g2w,
    const float* __restrict__ g2b,
    const float* __restrict__ W3,         // [32][2][128]
    const float* __restrict__ pb3,        // [32][2]
    const float* __restrict__ tsc,        // [32][2]
    const unsigned short* __restrict__ wscr,       // bf16 frag-ordered weights
    const unsigned char*  __restrict__ cvarpk,     // [B][32]
    const unsigned long long* __restrict__ adjbits,// [B][8]
    float* __restrict__ acc)                       // [B]
{
    __shared__ __align__(16) unsigned short XH[128][136];   // X then H (bf16)
    __shared__ float2 gnA[2][128];
    __shared__ float2 gnB[2][128];
    __shared__ float p_g1w[128], p_g1b[128], p_g2w[128], p_g2b[128], p_b1[128], p_b2[128];
    __shared__ float p_w3[2][128];
    __shared__ float p_b3[2], p_ts[2];
    __shared__ __align__(16) unsigned long long cvs[64][4];
    __shared__ __align__(16) unsigned long long abits_s[64][8];

    const int tid  = threadIdx.x;
    const int w    = tid >> 6, lane = tid & 63;
    const int lo   = lane & 15, hi = lane >> 4;
    const int wm   = w & 1, wn = w >> 1;
    const int l    = blockIdx.x & 31;
    const int grp  = blockIdx.x >> 5;

    const unsigned short* w1s = wscr + (size_t)((l * 2 + wm) * 16) * 512 + lane * 8;
    const unsigned short* w2s = wscr + (size_t)(((32 + l) * 2 + wm) * 16) * 512 + lane * 8;

    // ---- stage per-latent params + decisions ----
    if (tid < 128) {
        int c = tid;
        p_g1w[c] = g1w[l * 128 + c];  p_g1b[c] = g1b[l * 128 + c];
        p_b1[c]  = pb1[l * 128 + c];  p_w3[0][c] = W3[l * 256 + c];
    } else {
        int c = tid - 128;
        p_g2w[c] = g2w[l * 128 + c];  p_g2b[c] = g2b[l * 128 + c];
        p_b2[c]  = pb2[l * 128 + c];  p_w3[1][c] = W3[l * 256 + 128 + c];
    }
    if (tid == 0) {
        p_b3[0] = pb3[l * 2];  p_b3[1] = pb3[l * 2 + 1];
        p_ts[0] = tsc[l * 2];  p_ts[1] = tsc[l * 2 + 1];
    }
    if (tid < 128)
        ((uint4*)cvs)[tid] = ((const uint4*)(cvarpk + (size_t)grp * 64 * 32))[tid];
    ((uint4*)abits_s)[tid] = ((const uint4*)(adjbits + (size_t)grp * 64 * 8))[tid];
    __syncthreads();  // B0

    const float inv128 = 1.0f / 128.0f;

    for (int it = 0; it < 4; ++it) {
        // ===== build X tile (128 rows x 104 + zero pad), bf16, chunked =====
        {
            int r    = ((tid & 127) >> 1) + ((tid >> 7) << 6);
            int half = tid & 1;
            int bl   = it * 16 + (r >> 3);
            int bg   = grp * 64 + bl;
            unsigned long long lamB = cvs[bl][l >> 3] >> (8 * (l & 7));
            int lam = (int)(lamB & 7);
            int tf  = (int)(lamB >> 3) & 1;
            if (half == 0) {
                unsigned long long bits = abits_s[bl][r & 7];
                const float4* zp = (const float4*)(z_sample + bg * 32);
                #pragma unroll
                for (int wq = 0; wq < 4; ++wq) {
                    float4 a = zp[2 * wq], bq = zp[2 * wq + 1];
                    float zc[8] = {a.x, a.y, a.z, a.w, bq.x, bq.y, bq.z, bq.w};
                    unsigned long long cw = cvs[bl][wq];
                    union { uint4 u; unsigned short s[8]; } xm, xk;
                    #pragma unroll
                    for (int jb = 0; jb < 8; ++jb) {
                        int j   = wq * 8 + jb;
                        int kap = (int)((cw >> (8 * jb)) & 7);
                        bool m  = (((bits >> (kap * 8 + lam)) & 1ULL) != 0) && (j != l);
                        xm.s[jb] = m ? f2b(zc[jb]) : (unsigned short)0;
                        xk.s[jb] = m ? (unsigned short)0x3F80 : (unsigned short)0;
                    }
                    *(uint4*)&XH[r][wq * 8]      = xm.u;
                    *(uint4*)&XH[r][32 + wq * 8] = xk.u;
                }
            } else {
                union { uint4 u; unsigned short s[8]; } tv;
                #pragma unroll
                for (int kk = 0; kk < 8; ++kk)
                    tv.s[kk] = (tf && kk == lam) ? (unsigned short)0x3F80 : (unsigned short)0;
                *(uint4*)&XH[r][64] = tv.u;
                const float4* sp = (const float4*)(z_shared + bg * 32);
                #pragma unroll
                for (int q = 0; q < 4; ++q) {
                    float4 a = sp[2 * q], b = sp[2 * q + 1];
                    *(uint4*)&XH[r][72 + 8 * q] =
                        make_uint4(pk2(a.x, a.y), pk2(a.z, a.w), pk2(b.x, b.y), pk2(b.z, b.w));
                }
                uint4 zz = make_uint4(0u, 0u, 0u, 0u);
                *(uint4*)&XH[r][104] = zz;
                *(uint4*)&XH[r][112] = zz;
                *(uint4*)&XH[r][120] = zz;
            }
        }
        __syncthreads();  // B1

        // ================= GEMM1: D[c][row] = W1 * X^T =================
        f32x4 accr[4][4];
        #pragma unroll
        for (int a = 0; a < 4; ++a)
            #pragma unroll
            for (int bq = 0; bq < 4; ++bq) accr[a][bq] = (f32x4){0.f, 0.f, 0.f, 0.f};
        {
            bf16x8 wfr[4];
            #pragma unroll
            for (int mt = 0; mt < 4; ++mt) wfr[mt] = ld_frag(w1s + (mt * 4 + 0) * 512);
            #pragma unroll
            for (int ks = 0; ks < 4; ++ks) {
                bf16x8 bfr[4];
                #pragma unroll
                for (int nt = 0; nt < 4; ++nt)
                    bfr[nt] = ld_frag(&XH[16 * (4 * wn + nt) + lo][ks * 32 + hi * 8]);
                bf16x8 wnx[4];
                if (ks < 3) {
                    #pragma unroll
                    for (int mt = 0; mt < 4; ++mt)
                        wnx[mt] = ld_frag(w1s + (mt * 4 + ks + 1) * 512);
                }
                #pragma unroll
                for (int mt = 0; mt < 4; ++mt)
                    #pragma unroll
                    for (int nt = 0; nt < 4; ++nt)
                        accr[mt][nt] = __builtin_amdgcn_mfma_f32_16x16x32_bf16(
                            wfr[mt], bfr[nt], accr[mt][nt], 0, 0, 0);
                if (ks < 3) {
                    #pragma unroll
                    for (int mt = 0; mt < 4; ++mt) wfr[mt] = wnx[mt];
                }
            }
        }

        // ---- GN1 stats (bias included) ----
        float s1[4] = {0, 0, 0, 0}, s2[4] = {0, 0, 0, 0};
        #pragma unroll
        for (int mt = 0; mt < 4; ++mt) {
            int cb = 16 * (4 * wm + mt) + 4 * hi;
            #pragma unroll
            for (int rg = 0; rg < 4; ++rg) {
                float bias = p_b1[cb + rg];
                #pragma unroll
                for (int nt = 0; nt < 4; ++nt) {
                    float v = accr[mt][nt][rg] + bias;
                    accr[mt][nt][rg] = v;
                    s1[nt] += v; s2[nt] += v * v;
                }
            }
        }
        #pragma unroll
        for (int nt = 0; nt < 4; ++nt) {
            s1[nt] += __shfl_xor(s1[nt], 16, 64);  s1[nt] += __shfl_xor(s1[nt], 32, 64);
            s2[nt] += __shfl_xor(s2[nt], 16, 64);  s2[nt] += __shfl_xor(s2[nt], 32, 64);
        }
        if (hi == 0) {
            #pragma unroll
            for (int nt = 0; nt < 4; ++nt)
                gnA[wm][16 * (4 * wn + nt) + lo] = make_float2(s1[nt], s2[nt]);
        }
        __syncthreads();  // B2

        float mu[4], rstd[4];
        #pragma unroll
        for (int nt = 0; nt < 4; ++nt) {
            float2 a0 = gnA[0][16 * (4 * wn + nt) + lo];
            float2 a1 = gnA[1][16 * (4 * wn + nt) + lo];
            float m_  = (a0.x + a1.x) * inv128;
            float var = (a0.y + a1.y) * inv128 - m_ * m_;
            mu[nt] = m_;  rstd[nt] = rsqrtf(var + 1e-5f);
        }
        // ---- normalize + SiLU -> H ----
        #pragma unroll
        for (int mt = 0; mt < 4; ++mt) {
            int cb = 16 * (4 * wm + mt) + 4 * hi;
            #pragma unroll
            for (int nt = 0; nt < 4; ++nt) {
                int n = 16 * (4 * wn + nt) + lo;
                unsigned short us[4];
                #pragma unroll
                for (int rg = 0; rg < 4; ++rg) {
                    int c = cb + rg;
                    float x  = (accr[mt][nt][rg] - mu[nt]) * rstd[nt] * p_g1w[c] + p_g1b[c];
                    float sl = x / (1.0f + __expf(-x));
                    us[rg] = f2b(sl);
                }
                unsigned int w0 = (unsigned int)us[0] | ((unsigned int)us[1] << 16);
                unsigned int w1v = (unsigned int)us[2] | ((unsigned int)us[3] << 16);
                *(uint2*)&XH[n][cb] = make_uint2(w0, w1v);
            }
        }
        __syncthreads();  // B3

        // ================= GEMM2: D[c][row] = W2 * H^T =================
        #pragma unroll
        for (int a = 0; a < 4; ++a)
            #pragma unroll
            for (int bq = 0; bq < 4; ++bq) accr[a][bq] = (f32x4){0.f, 0.f, 0.f, 0.f};
        {
            bf16x8 wfr[4];
            #pragma unroll
            for (int mt = 0; mt < 4; ++mt) wfr[mt] = ld_frag(w2s + (mt * 4 + 0) * 512);
            #pragma unroll
            for (int ks = 0; ks < 4; ++ks) {
                bf16x8 bfr[4];
                #pragma unroll
                for (int nt = 0; nt < 4; ++nt)
                    bfr[nt] = ld_frag(&XH[16 * (4 * wn + nt) + lo][ks * 32 + hi * 8]);
                bf16x8 wnx[4];
                if (ks < 3) {
                    #pragma unroll
                    for (int mt = 0; mt < 4; ++mt)
                        wnx[mt] = ld_frag(w2s + (mt * 4 + ks + 1) * 512);
                }
                #pragma unroll
                for (int mt = 0; mt < 4; ++mt)
                    #pragma unroll
                    for (int nt = 0; nt < 4; ++nt)
                        accr[mt][nt] = __builtin_amdgcn_mfma_f32_16x16x32_bf16(
                            wfr[mt], bfr[nt], accr[mt][nt], 0, 0, 0);
                if (ks < 3) {
                    #pragma unroll
                    for (int mt = 0; mt < 4; ++mt) wfr[mt] = wnx[mt];
                }
            }
        }

        // ---- GN2 stats ----
        float t1[4] = {0, 0, 0, 0}, t2[4] = {0, 0, 0, 0};
        #pragma unroll
        for (int mt = 0; mt < 4; ++mt) {
            int cb = 16 * (4 * wm + mt) + 4 * hi;
            #pragma unroll
            for (int rg = 0; rg < 4; ++rg) {
                float bias = p_b2[cb + rg];
                #pragma unroll
                for (int nt = 0; nt < 4; ++nt) {
                    float v = accr[mt][nt][rg] + bias;
                    accr[mt][nt][rg] = v;
                    t1[nt] += v; t2[nt] += v * v;
                }
            }
        }
        #pragma unroll
        for (int nt = 0; nt < 4; ++nt) {
            t1[nt] += __shfl_xor(t1[nt], 16, 64);  t1[nt] += __shfl_xor(t1[nt], 32, 64);
            t2[nt] += __shfl_xor(t2[nt], 16, 64);  t2[nt] += __shfl_xor(t2[nt], 32, 64);
        }
        if (hi == 0) {
            #pragma unroll
            for (int nt = 0; nt < 4; ++nt)
                gnA[wm][16 * (4 * wn + nt) + lo] = make_float2(t1[nt], t2[nt]);
        }
        __syncthreads();  // B4

        // ---- normalize + SiLU + 128->2 dot partials ----
        float pmp[4] = {0, 0, 0, 0}, plp[4] = {0, 0, 0, 0};
        float mu2[4], rstd2[4];
        #pragma unroll
        for (int nt = 0; nt < 4; ++nt) {
            float2 a0 = gnA[0][16 * (4 * wn + nt) + lo];
            float2 a1 = gnA[1][16 * (4 * wn + nt) + lo];
            float m_  = (a0.x + a1.x) * inv128;
            float var = (a0.y + a1.y) * inv128 - m_ * m_;
            mu2[nt] = m_;  rstd2[nt] = rsqrtf(var + 1e-5f);
        }
        #pragma unroll
        for (int mt = 0; mt < 4; ++mt) {
            int cb = 16 * (4 * wm + mt) + 4 * hi;
            #pragma unroll
            for (int rg = 0; rg < 4; ++rg) {
                int c = cb + rg;
                float wg = p_g2w[c], bgn = p_g2b[c], w30 = p_w3[0][c], w31 = p_w3[1][c];
                #pragma unroll
                for (int nt = 0; nt < 4; ++nt) {
                    float x  = (accr[mt][nt][rg] - mu2[nt]) * rstd2[nt] * wg + bgn;
                    float sl = x / (1.0f + __expf(-x));
                    pmp[nt] += sl * w30;
                    plp[nt] += sl * w31;
                }
            }
        }
        #pragma unroll
        for (int nt = 0; nt < 4; ++nt) {
            pmp[nt] += __shfl_xor(pmp[nt], 16, 64);  pmp[nt] += __shfl_xor(pmp[nt], 32, 64);
            plp[nt] += __shfl_xor(plp[nt], 16, 64);  plp[nt] += __shfl_xor(plp[nt], 32, 64);
        }
        if (hi == 0) {
            #pragma unroll
            for (int nt = 0; nt < 4; ++nt)
                gnB[wm][16 * (4 * wn + nt) + lo] = make_float2(pmp[nt], plp[nt]);
        }
        __syncthreads();  // B5

        // ---- tanh-scale + KLD + mean over g + accumulate ----
        if (wm == 0 && hi == 0) {
            float sc0 = __expf(p_ts[0]), sc1 = __expf(p_ts[1]);
            #pragma unroll
            for (int nt = 0; nt < 4; ++nt) {
                int n = 16 * (4 * wn + nt) + lo;
                float2 q0 = gnB[0][n], q1 = gnB[1][n];
                float pm = q0.x + q1.x + p_b3[0];
                float pl = q0.y + q1.y + p_b3[1];
                pm = tanhf(pm / sc0) * sc0;
                pl = tanhf(pl / sc1) * sc1;
                int bl = it * 16 + (n >> 3);
                int bg = grp * 64 + bl;
                float zm = z_mean[bg * 32 + l];
                float zl = z_logstd[bg * 32 + l];
                float vq = __expf(2.0f * zl);
                float d  = zm - pm;
                float kld = pl - zl + (vq + d * d) * 0.5f * __expf(-2.0f * pl) - 0.5f;
                kld += __shfl_xor(kld, 1, 64);
                kld += __shfl_xor(kld, 2, 64);
                kld += __shfl_xor(kld, 4, 64);
                if ((lo & 7) == 0) atomicAdd(&acc[bg], kld * 0.125f);
            }
        }
    }
}

// ---------------------------------------------------------------------------
// Kernel 3: fp32 accumulator -> fp32 output
// ---------------------------------------------------------------------------
__global__ __launch_bounds__(256) void finish_kernel(const float* __restrict__ acc,
                                                     float* __restrict__ out) {
    int i = blockIdx.x * 256 + threadIdx.x;
    if (i < B_DIM) out[i] = acc[i];
}

extern "C" void kernel_launch(void* const* d_in, const int* in_sizes, int n_in,
                              void* d_out, int out_size, void* d_ws, size_t ws_size,
                              hipStream_t stream) {
    const float* z_sample      = (const float*)d_in[0];
    const int*   target        = (const int*)d_in[1];
    const float* z_mean        = (const float*)d_in[2];
    const float* z_logstd      = (const float*)d_in[3];
    const float* z_shared      = (const float*)d_in[4];
    const float* u_gumbel      = (const float*)d_in[5];
    const float* u_adj         = (const float*)d_in[6];
    const float* target_params = (const float*)d_in[7];
    const float* enco_theta    = (const float*)d_in[8];
    const float* enco_gamma    = (const float*)d_in[9];
    const float* W1            = (const float*)d_in[10];
    const float* pb1           = (const float*)d_in[11];
    const float* g1w           = (const float*)d_in[12];
    const float* g1b           = (const float*)d_in[13];
    const float* W2            = (const float*)d_in[14];
    const float* pb2           = (const float*)d_in[15];
    const float* g2w           = (const float*)d_in[16];
    const float* g2b           = (const float*)d_in[17];
    const float* W3            = (const float*)d_in[18];
    const float* pb3           = (const float*)d_in[19];
    const float* tsc           = (const float*)d_in[20];

    float*              acc     = (float*)d_ws;                                // 4 KB
    unsigned char*      cvarpk  = (unsigned char*)d_ws + 4096;                 // 32 KB
    unsigned long long* adjbits = (unsigned long long*)((char*)d_ws + 36864);  // 64 KB
    unsigned short*     wscr    = (unsigned short*)((char*)d_ws + 102400);     // 2 MB

    prep_kernel<<<1024, 256, 0, stream>>>(u_gumbel, u_adj, target_params,
                                          enco_theta, enco_gamma, target,
                                          acc, cvarpk, adjbits);
    wprep_kernel<<<512, 256, 0, stream>>>(W1, W2, wscr);
    fused_kernel<<<512, 256, 0, stream>>>(z_sample, z_mean, z_logstd, z_shared,
                                          pb1, g1w, g1b, pb2, g2w, g2b,
                                          W3, pb3, tsc, wscr, cvarpk, adjbits, acc);
    finish_kernel<<<4, 256, 0, stream>>>(acc, (float*)d_out);
}

// Round 5
// 199.922 us; speedup vs baseline: 1.0979x; 1.0979x over previous
//
#include <hip/hip_runtime.h>
#include <hip/hip_bf16.h>

// Problem constants
#define B_DIM 1024
#define L_DIM 32
#define K_DIM 8
#define G_DIM 8
#define C_DIM 128
#define S_DIM 32
#define DIN   104   // 2L + K + S

typedef __bf16  bf16x8 __attribute__((ext_vector_type(8)));
typedef float   f32x4  __attribute__((ext_vector_type(4)));

union frag_u { uint4 u; bf16x8 v; };

static __device__ __forceinline__ unsigned int pk2(float a, float b) {
    __hip_bfloat162 h = __float22bfloat162_rn(make_float2(a, b));  // v_cvt_pk_bf16_f32
    union { __hip_bfloat162 h; unsigned int u; } v; v.h = h; return v.u;
}
static __device__ __forceinline__ bf16x8 ld_frag(const unsigned short* p) {
    frag_u t; t.u = *(const uint4*)p; return t.v;
}

// ---------------------------------------------------------------------------
// Kernel 1 (merged): blocks [0,1024): per-b decisions in fp64 + zero d_out[b].
//                    blocks [1024,1536): W1/W2 fp32->bf16 fragment repack.
// ---------------------------------------------------------------------------
__global__ __launch_bounds__(256) void prep_kernel(
    const float* __restrict__ u_gumbel,      // [B,L,K]
    const float* __restrict__ u_adj,         // [B,G,K,K]
    const float* __restrict__ target_params, // [L,K]
    const float* __restrict__ enco_theta,    // [K,K]
    const float* __restrict__ enco_gamma,    // [K,K]
    const int*   __restrict__ target,        // [B]
    const float* __restrict__ W1,            // [32][128][104]
    const float* __restrict__ W2,            // [32][128][128]
    float*       __restrict__ out,           // [B] (zeroed here, atomics later)
    unsigned char* __restrict__ cvarpk,      // [B][32]  cvar | tflag<<3
    unsigned long long* __restrict__ adjbits,// [B][8]
    unsigned short* __restrict__ wscr)       // bf16 frag-ordered weights
{
    const int t = threadIdx.x;
    if (blockIdx.x >= 1024) {
        // ---- weight repack: frag F = ((which*32+l)*2+wm)*16 + mt*4+ks ----
        int gtid  = (blockIdx.x - 1024) * 256 + t;   // [0, 131072)
        int lane  = gtid & 63;
        int ks    = (gtid >> 6) & 3;
        int mt    = (gtid >> 8) & 3;
        int wm    = (gtid >> 10) & 1;
        int l     = (gtid >> 11) & 31;
        int which = gtid >> 16;
        int m  = 16 * (4 * wm + mt) + (lane & 15);
        int k0 = ks * 32 + (lane >> 4) * 8;
        uint4 o;
        if (which == 0) {
            if (k0 >= 104) {
                o = make_uint4(0u, 0u, 0u, 0u);
            } else {
                const float* p = W1 + (size_t)l * 13312 + m * 104 + k0;
                float4 a = *(const float4*)p, bq = *(const float4*)(p + 4);
                o = make_uint4(pk2(a.x, a.y), pk2(a.z, a.w), pk2(bq.x, bq.y), pk2(bq.z, bq.w));
            }
        } else {
            const float* p = W2 + (size_t)l * 16384 + m * 128 + k0;
            float4 a = *(const float4*)p, bq = *(const float4*)(p + 4);
            o = make_uint4(pk2(a.x, a.y), pk2(a.z, a.w), pk2(bq.x, bq.y), pk2(bq.z, bq.w));
        }
        *(uint4*)(wscr + (size_t)gtid * 8) = o;
        return;
    }

    __shared__ double ep[64];
    const int b = blockIdx.x;
    if (t < 64) {
        double th = (double)enco_theta[t];
        double ga = (double)enco_gamma[t];
        ep[t] = (1.0 / (1.0 + exp(-th))) * (1.0 / (1.0 + exp(-ga)));
    }
    if (t == 0) out[b] = 0.0f;
    __syncthreads();

    // gumbel argmax: thread t = l*8 + k; 8-lane subgroup reduction
    {
        const int l = t >> 3, k = t & 7;
        double u = (double)u_gumbel[b * 256 + t];
        double g = -log(-log(u + 1e-10) + 1e-10);
        double v = (double)target_params[t] + g;   // TAU = 1
        int bk = k;
        #pragma unroll
        for (int off = 1; off < 8; off <<= 1) {
            double ov = __shfl_xor(v, off, 64);
            int   obk = __shfl_xor(bk, off, 64);
            if (ov > v || (ov == v && obk < bk)) { v = ov; bk = obk; }
        }
        if (k == 0) {
            int tg = target[b];
            cvarpk[b * 32 + l] = (unsigned char)(bk | ((bk == tg) ? 8 : 0));
        }
    }
    // adjacency: wave w handles g = w and g = w+4
    {
        const int wv = t >> 6, lane = t & 63;
        #pragma unroll
        for (int q = 0; q < 2; ++q) {
            int gg = wv + 4 * q;
            double u = (double)u_adj[b * 512 + gg * 64 + lane];
            unsigned long long m = __ballot(u < ep[lane]);
            if (lane == 0) adjbits[b * 8 + gg] = m;
        }
    }
}

// ---------------------------------------------------------------------------
// Kernel 2: fused build-X + GEMM1 + GN1 + SiLU + GEMM2 + GN2 + SiLU + GEMM3 +
// tanh-scale + KLD + g-mean, atomicAdd into out[b].
// Grid 512: l = blockIdx&31, grp = blockIdx>>5. 4 tiles of 128 rows; 4 waves
// tile D[c][row] 2x2. Weight fragments streamed from bf16 scratch per ks.
// launch_bounds(256,2): 2 blocks/CU (VGPR ~200 <= 256), no spill.
// Build-X split is WAVE-UNIFORM: waves 0-1 masked-z cols, waves 2-3 tail cols.
// ---------------------------------------------------------------------------
__global__ __launch_bounds__(256, 2) void fused_kernel(
    const float* __restrict__ z_sample,   // [B,32]
    const float* __restrict__ z_mean,     // [B,32]
    const float* __restrict__ z_logstd,   // [B,32]
    const float* __restrict__ z_shared,   // [B,32]
    const float* __restrict__ pb1,        // [32][128]
    const float* __restrict__ g1w,
    const float* __restrict__ g1b,
    const float* __restrict__ pb2,
    const float* __restrict__ g2w,
    const float* __restrict__ g2b,
    const float* __restrict__ W3,         // [32][2][128]
    const float* __restrict__ pb3,        // [32][2]
    const float* __restrict__ tsc,        // [32][2]
    const unsigned short* __restrict__ wscr,       // bf16 frag-ordered weights
    const unsigned char*  __restrict__ cvarpk,     // [B][32]
    const unsigned long long* __restrict__ adjbits,// [B][8]
    float* __restrict__ out)                       // [B]
{
    __shared__ __align__(16) unsigned short XH[128][136];   // X then H (bf16)
    __shared__ float2 gnA[2][128];
    __shared__ float2 gnB[2][128];
    __shared__ float p_g1w[128], p_g1b[128], p_g2w[128], p_g2b[128], p_b1[128], p_b2[128];
    __shared__ float p_w3[2][128];
    __shared__ float p_b3[2], p_ts[2];
    __shared__ __align__(16) unsigned long long cvs[64][4];
    __shared__ __align__(16) unsigned long long abits_s[64][8];

    const int tid  = threadIdx.x;
    const int w    = tid >> 6, lane = tid & 63;
    const int lo   = lane & 15, hi = lane >> 4;
    const int wm   = w & 1, wn = w >> 1;
    const int l    = blockIdx.x & 31;
    const int grp  = blockIdx.x >> 5;

    const unsigned short* w1s = wscr + (size_t)((l * 2 + wm) * 16) * 512 + lane * 8;
    const unsigned short* w2s = wscr + (size_t)(((32 + l) * 2 + wm) * 16) * 512 + lane * 8;

    // ---- stage per-latent params + decisions ----
    if (tid < 128) {
        int c = tid;
        p_g1w[c] = g1w[l * 128 + c];  p_g1b[c] = g1b[l * 128 + c];
        p_b1[c]  = pb1[l * 128 + c];  p_w3[0][c] = W3[l * 256 + c];
    } else {
        int c = tid - 128;
        p_g2w[c] = g2w[l * 128 + c];  p_g2b[c] = g2b[l * 128 + c];
        p_b2[c]  = pb2[l * 128 + c];  p_w3[1][c] = W3[l * 256 + 128 + c];
    }
    if (tid == 0) {
        p_b3[0] = pb3[l * 2];  p_b3[1] = pb3[l * 2 + 1];
        p_ts[0] = tsc[l * 2];  p_ts[1] = tsc[l * 2 + 1];
    }
    if (tid < 128)
        ((uint4*)cvs)[tid] = ((const uint4*)(cvarpk + (size_t)grp * 64 * 32))[tid];
    ((uint4*)abits_s)[tid] = ((const uint4*)(adjbits + (size_t)grp * 64 * 8))[tid];
    __syncthreads();  // B0

    const float inv128 = 1.0f / 128.0f;

    for (int it = 0; it < 4; ++it) {
        // ===== build X tile (128 rows x 104 + pad): wave-uniform split =====
        {
            int r  = tid & 127;                 // row
            int bl = it * 16 + (r >> 3);
            int bg = grp * 64 + bl;
            unsigned long long lamB = cvs[bl][l >> 3] >> (8 * (l & 7));
            int lam = (int)(lamB & 7);
            if (tid < 128) {
                // masked z + mask indicator (cols 0..63)
                unsigned long long bits = abits_s[bl][r & 7];
                const float4* zp = (const float4*)(z_sample + bg * 32);
                #pragma unroll
                for (int wq = 0; wq < 4; ++wq) {
                    float4 a = zp[2 * wq], bq = zp[2 * wq + 1];
                    unsigned long long cw = cvs[bl][wq];
                    float zc0 = a.x, zc1 = a.y, zc2 = a.z, zc3 = a.w;
                    float zc4 = bq.x, zc5 = bq.y, zc6 = bq.z, zc7 = bq.w;
                    bool mm[8];
                    #pragma unroll
                    for (int jb = 0; jb < 8; ++jb) {
                        int j   = wq * 8 + jb;
                        int kap = (int)((cw >> (8 * jb)) & 7);
                        mm[jb]  = (((bits >> (kap * 8 + lam)) & 1ULL) != 0) && (j != l);
                    }
                    uint4 xm, xk;
                    xm.x = pk2(mm[0] ? zc0 : 0.f, mm[1] ? zc1 : 0.f);
                    xm.y = pk2(mm[2] ? zc2 : 0.f, mm[3] ? zc3 : 0.f);
                    xm.z = pk2(mm[4] ? zc4 : 0.f, mm[5] ? zc5 : 0.f);
                    xm.w = pk2(mm[6] ? zc6 : 0.f, mm[7] ? zc7 : 0.f);
                    xk.x = (mm[0] ? 0x3F80u : 0u) | (mm[1] ? 0x3F800000u : 0u);
                    xk.y = (mm[2] ? 0x3F80u : 0u) | (mm[3] ? 0x3F800000u : 0u);
                    xk.z = (mm[4] ? 0x3F80u : 0u) | (mm[5] ? 0x3F800000u : 0u);
                    xk.w = (mm[6] ? 0x3F80u : 0u) | (mm[7] ? 0x3F800000u : 0u);
                    *(uint4*)&XH[r][wq * 8]      = xm;
                    *(uint4*)&XH[r][32 + wq * 8] = xk;
                }
            } else {
                // target one-hot (cols 64..71) + shared (72..103) + pad (104..127)
                int tf = (int)(lamB >> 3) & 1;
                union { uint4 u; unsigned short s[8]; } tv;
                #pragma unroll
                for (int kk = 0; kk < 8; ++kk)
                    tv.s[kk] = (tf && kk == lam) ? (unsigned short)0x3F80 : (unsigned short)0;
                *(uint4*)&XH[r][64] = tv.u;
                const float4* sp = (const float4*)(z_shared + bg * 32);
                #pragma unroll
                for (int q = 0; q < 4; ++q) {
                    float4 a = sp[2 * q], b = sp[2 * q + 1];
                    *(uint4*)&XH[r][72 + 8 * q] =
                        make_uint4(pk2(a.x, a.y), pk2(a.z, a.w), pk2(b.x, b.y), pk2(b.z, b.w));
                }
                uint4 zz = make_uint4(0u, 0u, 0u, 0u);
                *(uint4*)&XH[r][104] = zz;
                *(uint4*)&XH[r][112] = zz;
                *(uint4*)&XH[r][120] = zz;
            }
        }
        __syncthreads();  // B1

        // ================= GEMM1: D[c][row] = W1 * X^T =================
        f32x4 accr[4][4];
        #pragma unroll
        for (int a = 0; a < 4; ++a)
            #pragma unroll
            for (int bq = 0; bq < 4; ++bq) accr[a][bq] = (f32x4){0.f, 0.f, 0.f, 0.f};
        {
            bf16x8 wfr[4];
            #pragma unroll
            for (int mt = 0; mt < 4; ++mt) wfr[mt] = ld_frag(w1s + (mt * 4 + 0) * 512);
            #pragma unroll
            for (int ks = 0; ks < 4; ++ks) {
                bf16x8 bfr[4];
                #pragma unroll
                for (int nt = 0; nt < 4; ++nt)
                    bfr[nt] = ld_frag(&XH[16 * (4 * wn + nt) + lo][ks * 32 + hi * 8]);
                bf16x8 wnx[4];
                if (ks < 3) {
                    #pragma unroll
                    for (int mt = 0; mt < 4; ++mt)
                        wnx[mt] = ld_frag(w1s + (mt * 4 + ks + 1) * 512);
                }
                #pragma unroll
                for (int mt = 0; mt < 4; ++mt)
                    #pragma unroll
                    for (int nt = 0; nt < 4; ++nt)
                        accr[mt][nt] = __builtin_amdgcn_mfma_f32_16x16x32_bf16(
                            wfr[mt], bfr[nt], accr[mt][nt], 0, 0, 0);
                if (ks < 3) {
                    #pragma unroll
                    for (int mt = 0; mt < 4; ++mt) wfr[mt] = wnx[mt];
                }
            }
        }

        // ---- GN1 stats (bias included) ----
        float s1[4] = {0, 0, 0, 0}, s2[4] = {0, 0, 0, 0};
        #pragma unroll
        for (int mt = 0; mt < 4; ++mt) {
            int cb = 16 * (4 * wm + mt) + 4 * hi;
            #pragma unroll
            for (int rg = 0; rg < 4; ++rg) {
                float bias = p_b1[cb + rg];
                #pragma unroll
                for (int nt = 0; nt < 4; ++nt) {
                    float v = accr[mt][nt][rg] + bias;
                    accr[mt][nt][rg] = v;
                    s1[nt] += v; s2[nt] += v * v;
                }
            }
        }
        #pragma unroll
        for (int nt = 0; nt < 4; ++nt) {
            s1[nt] += __shfl_xor(s1[nt], 16, 64);  s1[nt] += __shfl_xor(s1[nt], 32, 64);
            s2[nt] += __shfl_xor(s2[nt], 16, 64);  s2[nt] += __shfl_xor(s2[nt], 32, 64);
        }
        if (hi == 0) {
            #pragma unroll
            for (int nt = 0; nt < 4; ++nt)
                gnA[wm][16 * (4 * wn + nt) + lo] = make_float2(s1[nt], s2[nt]);
        }
        __syncthreads();  // B2

        float mu[4], rstd[4];
        #pragma unroll
        for (int nt = 0; nt < 4; ++nt) {
            float2 a0 = gnA[0][16 * (4 * wn + nt) + lo];
            float2 a1 = gnA[1][16 * (4 * wn + nt) + lo];
            float m_  = (a0.x + a1.x) * inv128;
            float var = (a0.y + a1.y) * inv128 - m_ * m_;
            mu[nt] = m_;  rstd[nt] = rsqrtf(var + 1e-5f);
        }
        // ---- normalize + SiLU -> H ----
        #pragma unroll
        for (int mt = 0; mt < 4; ++mt) {
            int cb = 16 * (4 * wm + mt) + 4 * hi;
            #pragma unroll
            for (int nt = 0; nt < 4; ++nt) {
                int n = 16 * (4 * wn + nt) + lo;
                float sl[4];
                #pragma unroll
                for (int rg = 0; rg < 4; ++rg) {
                    int c = cb + rg;
                    float x = (accr[mt][nt][rg] - mu[nt]) * rstd[nt] * p_g1w[c] + p_g1b[c];
                    sl[rg]  = __fdividef(x, 1.0f + __expf(-x));
                }
                *(uint2*)&XH[n][cb] = make_uint2(pk2(sl[0], sl[1]), pk2(sl[2], sl[3]));
            }
        }
        __syncthreads();  // B3

        // ================= GEMM2: D[c][row] = W2 * H^T =================
        #pragma unroll
        for (int a = 0; a < 4; ++a)
            #pragma unroll
            for (int bq = 0; bq < 4; ++bq) accr[a][bq] = (f32x4){0.f, 0.f, 0.f, 0.f};
        {
            bf16x8 wfr[4];
            #pragma unroll
            for (int mt = 0; mt < 4; ++mt) wfr[mt] = ld_frag(w2s + (mt * 4 + 0) * 512);
            #pragma unroll
            for (int ks = 0; ks < 4; ++ks) {
                bf16x8 bfr[4];
                #pragma unroll
                for (int nt = 0; nt < 4; ++nt)
                    bfr[nt] = ld_frag(&XH[16 * (4 * wn + nt) + lo][ks * 32 + hi * 8]);
                bf16x8 wnx[4];
                if (ks < 3) {
                    #pragma unroll
                    for (int mt = 0; mt < 4; ++mt)
                        wnx[mt] = ld_frag(w2s + (mt * 4 + ks + 1) * 512);
                }
                #pragma unroll
                for (int mt = 0; mt < 4; ++mt)
                    #pragma unroll
                    for (int nt = 0; nt < 4; ++nt)
                        accr[mt][nt] = __builtin_amdgcn_mfma_f32_16x16x32_bf16(
                            wfr[mt], bfr[nt], accr[mt][nt], 0, 0, 0);
                if (ks < 3) {
                    #pragma unroll
                    for (int mt = 0; mt < 4; ++mt) wfr[mt] = wnx[mt];
                }
            }
        }

        // ---- GN2 stats ----
        float t1[4] = {0, 0, 0, 0}, t2[4] = {0, 0, 0, 0};
        #pragma unroll
        for (int mt = 0; mt < 4; ++mt) {
            int cb = 16 * (4 * wm + mt) + 4 * hi;
            #pragma unroll
            for (int rg = 0; rg < 4; ++rg) {
                float bias = p_b2[cb + rg];
                #pragma unroll
                for (int nt = 0; nt < 4; ++nt) {
                    float v = accr[mt][nt][rg] + bias;
                    accr[mt][nt][rg] = v;
                    t1[nt] += v; t2[nt] += v * v;
                }
            }
        }
        #pragma unroll
        for (int nt = 0; nt < 4; ++nt) {
            t1[nt] += __shfl_xor(t1[nt], 16, 64);  t1[nt] += __shfl_xor(t1[nt], 32, 64);
            t2[nt] += __shfl_xor(t2[nt], 16, 64);  t2[nt] += __shfl_xor(t2[nt], 32, 64);
        }
        if (hi == 0) {
            #pragma unroll
            for (int nt = 0; nt < 4; ++nt)
                gnA[wm][16 * (4 * wn + nt) + lo] = make_float2(t1[nt], t2[nt]);
        }
        __syncthreads();  // B4

        // ---- normalize + SiLU + 128->2 dot partials ----
        float pmp[4] = {0, 0, 0, 0}, plp[4] = {0, 0, 0, 0};
        float mu2[4], rstd2[4];
        #pragma unroll
        for (int nt = 0; nt < 4; ++nt) {
            float2 a0 = gnA[0][16 * (4 * wn + nt) + lo];
            float2 a1 = gnA[1][16 * (4 * wn + nt) + lo];
            float m_  = (a0.x + a1.x) * inv128;
            float var = (a0.y + a1.y) * inv128 - m_ * m_;
            mu2[nt] = m_;  rstd2[nt] = rsqrtf(var + 1e-5f);
        }
        #pragma unroll
        for (int mt = 0; mt < 4; ++mt) {
            int cb = 16 * (4 * wm + mt) + 4 * hi;
            #pragma unroll
            for (int rg = 0; rg < 4; ++rg) {
                int c = cb + rg;
                float wg = p_g2w[c], bgn = p_g2b[c], w30 = p_w3[0][c], w31 = p_w3[1][c];
                #pragma unroll
                for (int nt = 0; nt < 4; ++nt) {
                    float x  = (accr[mt][nt][rg] - mu2[nt]) * rstd2[nt] * wg + bgn;
                    float sl = __fdividef(x, 1.0f + __expf(-x));
                    pmp[nt] += sl * w30;
                    plp[nt] += sl * w31;
                }
            }
        }
        #pragma unroll
        for (int nt = 0; nt < 4; ++nt) {
            pmp[nt] += __shfl_xor(pmp[nt], 16, 64);  pmp[nt] += __shfl_xor(pmp[nt], 32, 64);
            plp[nt] += __shfl_xor(plp[nt], 16, 64);  plp[nt] += __shfl_xor(plp[nt], 32, 64);
        }
        if (hi == 0) {
            #pragma unroll
            for (int nt = 0; nt < 4; ++nt)
                gnB[wm][16 * (4 * wn + nt) + lo] = make_float2(pmp[nt], plp[nt]);
        }
        __syncthreads();  // B5

        // ---- tanh-scale + KLD + mean over g + accumulate ----
        if (wm == 0 && hi == 0) {
            float sc0 = __expf(p_ts[0]), sc1 = __expf(p_ts[1]);
            #pragma unroll
            for (int nt = 0; nt < 4; ++nt) {
                int n = 16 * (4 * wn + nt) + lo;
                float2 q0 = gnB[0][n], q1 = gnB[1][n];
                float pm = q0.x + q1.x + p_b3[0];
                float pl = q0.y + q1.y + p_b3[1];
                pm = tanhf(pm / sc0) * sc0;
                pl = tanhf(pl / sc1) * sc1;
                int bl = it * 16 + (n >> 3);
                int bg = grp * 64 + bl;
                float zm = z_mean[bg * 32 + l];
                float zl = z_logstd[bg * 32 + l];
                float vq = __expf(2.0f * zl);
                float d  = zm - pm;
                float kld = pl - zl + (vq + d * d) * 0.5f * __expf(-2.0f * pl) - 0.5f;
                kld += __shfl_xor(kld, 1, 64);
                kld += __shfl_xor(kld, 2, 64);
                kld += __shfl_xor(kld, 4, 64);
                if ((lo & 7) == 0) atomicAdd(&out[bg], kld * 0.125f);
            }
        }
    }
}

extern "C" void kernel_launch(void* const* d_in, const int* in_sizes, int n_in,
                              void* d_out, int out_size, void* d_ws, size_t ws_size,
                              hipStream_t stream) {
    const float* z_sample      = (const float*)d_in[0];
    const int*   target        = (const int*)d_in[1];
    const float* z_mean        = (const float*)d_in[2];
    const float* z_logstd      = (const float*)d_in[3];
    const float* z_shared      = (const float*)d_in[4];
    const float* u_gumbel      = (const float*)d_in[5];
    const float* u_adj         = (const float*)d_in[6];
    const float* target_params = (const float*)d_in[7];
    const float* enco_theta    = (const float*)d_in[8];
    const float* enco_gamma    = (const float*)d_in[9];
    const float* W1            = (const float*)d_in[10];
    const float* pb1           = (const float*)d_in[11];
    const float* g1w           = (const float*)d_in[12];
    const float* g1b           = (const float*)d_in[13];
    const float* W2            = (const float*)d_in[14];
    const float* pb2           = (const float*)d_in[15];
    const float* g2w           = (const float*)d_in[16];
    const float* g2b           = (const float*)d_in[17];
    const float* W3            = (const float*)d_in[18];
    const float* pb3           = (const float*)d_in[19];
    const float* tsc           = (const float*)d_in[20];

    unsigned char*      cvarpk  = (unsigned char*)d_ws;                        // 32 KB
    unsigned long long* adjbits = (unsigned long long*)((char*)d_ws + 32768);  // 64 KB
    unsigned short*     wscr    = (unsigned short*)((char*)d_ws + 98304);      // 2 MB

    prep_kernel<<<1536, 256, 0, stream>>>(u_gumbel, u_adj, target_params,
                                          enco_theta, enco_gamma, target,
                                          W1, W2, (float*)d_out,
                                          cvarpk, adjbits, wscr);
    fused_kernel<<<512, 256, 0, stream>>>(z_sample, z_mean, z_logstd, z_shared,
                                          pb1, g1w, g1b, pb2, g2w, g2b,
                                          W3, pb3, tsc, wscr, cvarpk, adjbits,
                                          (float*)d_out);
}

// Round 6
// 180.027 us; speedup vs baseline: 1.2193x; 1.1105x over previous
//
#include <hip/hip_runtime.h>
#include <hip/hip_bf16.h>

// Problem constants
#define B_DIM 1024
#define L_DIM 32
#define K_DIM 8
#define G_DIM 8
#define C_DIM 128
#define S_DIM 32
#define DIN   104   // 2L + K + S

typedef __bf16  bf16x8 __attribute__((ext_vector_type(8)));
typedef float   f32x4  __attribute__((ext_vector_type(4)));

union frag_u { uint4 u; bf16x8 v; };

static __device__ __forceinline__ unsigned int pk2(float a, float b) {
    __hip_bfloat162 h = __float22bfloat162_rn(make_float2(a, b));  // v_cvt_pk_bf16_f32
    union { __hip_bfloat162 h; unsigned int u; } v; v.h = h; return v.u;
}
static __device__ __forceinline__ bf16x8 ld_frag(const unsigned short* p) {
    frag_u t; t.u = *(const uint4*)p; return t.v;
}

// ---------------------------------------------------------------------------
// Kernel 1 (merged): blocks [0,1024): per-b decisions (fp64) -> cvarpk byte +
//   precomputed parent-mask bits mask32[l][b][g]; zero d_out[b].
//   blocks [1024,1536): W1/W2 fp32->bf16 fragment repack.
// ---------------------------------------------------------------------------
__global__ __launch_bounds__(256) void prep_kernel(
    const float* __restrict__ u_gumbel,      // [B,L,K]
    const float* __restrict__ u_adj,         // [B,G,K,K]
    const float* __restrict__ target_params, // [L,K]
    const float* __restrict__ enco_theta,    // [K,K]
    const float* __restrict__ enco_gamma,    // [K,K]
    const int*   __restrict__ target,        // [B]
    const float* __restrict__ W1,            // [32][128][104]
    const float* __restrict__ W2,            // [32][128][128]
    float*       __restrict__ out,           // [B] (zeroed here, atomics later)
    unsigned char* __restrict__ cvarpk,      // [B][32]  cvar | tflag<<3
    unsigned int*  __restrict__ wsmask,      // [L][B][G] parent-mask bits over j
    unsigned short* __restrict__ wscr)       // bf16 frag-ordered weights
{
    const int t = threadIdx.x;
    if (blockIdx.x >= 1024) {
        // ---- weight repack: frag F = ((which*32+l)*2+wm)*16 + mt*4+ks ----
        int gtid  = (blockIdx.x - 1024) * 256 + t;   // [0, 131072)
        int lane  = gtid & 63;
        int ks    = (gtid >> 6) & 3;
        int mt    = (gtid >> 8) & 3;
        int wm    = (gtid >> 10) & 1;
        int l     = (gtid >> 11) & 31;
        int which = gtid >> 16;
        int m  = 16 * (4 * wm + mt) + (lane & 15);
        int k0 = ks * 32 + (lane >> 4) * 8;
        uint4 o;
        if (which == 0) {
            if (k0 >= 104) {
                o = make_uint4(0u, 0u, 0u, 0u);
            } else {
                const float* p = W1 + (size_t)l * 13312 + m * 104 + k0;
                float4 a = *(const float4*)p, bq = *(const float4*)(p + 4);
                o = make_uint4(pk2(a.x, a.y), pk2(a.z, a.w), pk2(bq.x, bq.y), pk2(bq.z, bq.w));
            }
        } else {
            const float* p = W2 + (size_t)l * 16384 + m * 128 + k0;
            float4 a = *(const float4*)p, bq = *(const float4*)(p + 4);
            o = make_uint4(pk2(a.x, a.y), pk2(a.z, a.w), pk2(bq.x, bq.y), pk2(bq.z, bq.w));
        }
        *(uint4*)(wscr + (size_t)gtid * 8) = o;
        return;
    }

    __shared__ double ep[64];
    __shared__ unsigned char cv8[32];
    __shared__ unsigned long long adjb[8];
    const int b = blockIdx.x;
    if (t < 64) {
        double th = (double)enco_theta[t];
        double ga = (double)enco_gamma[t];
        ep[t] = (1.0 / (1.0 + exp(-th))) * (1.0 / (1.0 + exp(-ga)));
    }
    if (t == 0) out[b] = 0.0f;
    __syncthreads();

    // gumbel argmax: thread t = l*8 + k; 8-lane subgroup reduction
    {
        const int l = t >> 3, k = t & 7;
        double u = (double)u_gumbel[b * 256 + t];
        double g = -log(-log(u + 1e-10) + 1e-10);
        double v = (double)target_params[t] + g;   // TAU = 1
        int bk = k;
        #pragma unroll
        for (int off = 1; off < 8; off <<= 1) {
            double ov = __shfl_xor(v, off, 64);
            int   obk = __shfl_xor(bk, off, 64);
            if (ov > v || (ov == v && obk < bk)) { v = ov; bk = obk; }
        }
        if (k == 0) {
            int tg = target[b];
            unsigned char pkd = (unsigned char)(bk | ((bk == tg) ? 8 : 0));
            cvarpk[b * 32 + l] = pkd;
            cv8[l] = pkd;
        }
    }
    // adjacency: wave w handles g = w and g = w+4; bits into LDS only
    {
        const int wv = t >> 6, lane = t & 63;
        #pragma unroll
        for (int q = 0; q < 2; ++q) {
            int gg = wv + 4 * q;
            double u = (double)u_adj[b * 512 + gg * 64 + lane];
            unsigned long long m = __ballot(u < ep[lane]);
            if (lane == 0) adjb[gg] = m;
        }
    }
    __syncthreads();

    // parent-mask: thread (g = t>>5, l = t&31): bit j = adj[g][cvar_j][cvar_l], j!=l
    {
        const int g = t >> 5, l = t & 31;
        int lam = cv8[l] & 7;
        unsigned long long bits = adjb[g] >> lam;   // bit (kap*8) now selects
        unsigned int mask = 0u;
        #pragma unroll
        for (int j = 0; j < 32; ++j) {
            int kap = cv8[j] & 7;
            mask |= ((unsigned int)(bits >> (kap * 8)) & 1u) << j;
        }
        mask &= ~(1u << l);
        wsmask[l * 8192 + b * 8 + g] = mask;
    }
}

// ---------------------------------------------------------------------------
// Kernel 2: fused build-X + GEMM1 + GN1 + SiLU + GEMM2 + GN2 + SiLU + GEMM3 +
// tanh-scale + KLD + g-mean, atomicAdd into out[b].
// Grid 2048: l = blockIdx&31 (same-l -> same XCD -> weights L2-resident),
// grp = blockIdx>>5 spans batches [grp*16, +16) -> ONE 128-row tile
// (16 b x 8 g). 4 waves tile D[c][row] 2x2. 3 blocks/CU resident (LDS ~44KB).
// ---------------------------------------------------------------------------
__global__ __launch_bounds__(256, 2) void fused_kernel(
    const float* __restrict__ z_sample,   // [B,32]
    const float* __restrict__ z_mean,     // [B,32]
    const float* __restrict__ z_logstd,   // [B,32]
    const float* __restrict__ z_shared,   // [B,32]
    const float* __restrict__ pb1,        // [32][128]
    const float* __restrict__ g1w,
    const float* __restrict__ g1b,
    const float* __restrict__ pb2,
    const float* __restrict__ g2w,
    const float* __restrict__ g2b,
    const float* __restrict__ W3,         // [32][2][128]
    const float* __restrict__ pb3,        // [32][2]
    const float* __restrict__ tsc,        // [32][2]
    const unsigned short* __restrict__ wscr,    // bf16 frag-ordered weights
    const unsigned char*  __restrict__ cvarpk,  // [B][32]
    const unsigned int*   __restrict__ wsmask,  // [L][B][G]
    float* __restrict__ out)                    // [B]
{
    __shared__ __align__(16) unsigned short XH[128][136];   // X then H (bf16)
    __shared__ float2 gnA[2][128];
    __shared__ float2 gnB[2][128];
    __shared__ float p_g1w[128], p_g1b[128], p_g2w[128], p_g2b[128], p_b1[128], p_b2[128];
    __shared__ float p_w3[2][128];
    __shared__ float p_b3[2], p_ts[2];
    __shared__ __align__(16) unsigned long long cvs[16][4];  // cvar bytes, 16 b

    const int tid  = threadIdx.x;
    const int w    = tid >> 6, lane = tid & 63;
    const int lo   = lane & 15, hi = lane >> 4;
    const int wm   = w & 1, wn = w >> 1;
    const int l    = blockIdx.x & 31;
    const int grp  = blockIdx.x >> 5;

    const unsigned short* w1s = wscr + (size_t)((l * 2 + wm) * 16) * 512 + lane * 8;
    const unsigned short* w2s = wscr + (size_t)(((32 + l) * 2 + wm) * 16) * 512 + lane * 8;

    // ---- stage per-latent params + decisions ----
    if (tid < 128) {
        int c = tid;
        p_g1w[c] = g1w[l * 128 + c];  p_g1b[c] = g1b[l * 128 + c];
        p_b1[c]  = pb1[l * 128 + c];  p_w3[0][c] = W3[l * 256 + c];
    } else {
        int c = tid - 128;
        p_g2w[c] = g2w[l * 128 + c];  p_g2b[c] = g2b[l * 128 + c];
        p_b2[c]  = pb2[l * 128 + c];  p_w3[1][c] = W3[l * 256 + 128 + c];
    }
    if (tid == 0) {
        p_b3[0] = pb3[l * 2];  p_b3[1] = pb3[l * 2 + 1];
        p_ts[0] = tsc[l * 2];  p_ts[1] = tsc[l * 2 + 1];
    }
    if (tid < 32)
        ((uint4*)cvs)[tid] = ((const uint4*)(cvarpk + (size_t)grp * 16 * 32))[tid];
    __syncthreads();  // B0

    const float inv128 = 1.0f / 128.0f;

    // ===== build X tile (128 rows x 104 + pad): wave-uniform split =====
    {
        int r  = tid & 127;                 // row = bl*8 + g
        int bl = r >> 3;
        int bg = grp * 16 + bl;
        if (tid < 128) {
            // masked z + mask indicator (cols 0..63)
            unsigned int m32 = wsmask[l * 8192 + (size_t)bg * 8 + (r & 7)];
            const float4* zp = (const float4*)(z_sample + bg * 32);
            #pragma unroll
            for (int wq = 0; wq < 4; ++wq) {
                float4 a = zp[2 * wq], bq = zp[2 * wq + 1];
                unsigned int mq = m32 >> (wq * 8);
                bool mm[8];
                #pragma unroll
                for (int jb = 0; jb < 8; ++jb) mm[jb] = (mq >> jb) & 1u;
                uint4 xm, xk;
                xm.x = pk2(mm[0] ? a.x : 0.f, mm[1] ? a.y : 0.f);
                xm.y = pk2(mm[2] ? a.z : 0.f, mm[3] ? a.w : 0.f);
                xm.z = pk2(mm[4] ? bq.x : 0.f, mm[5] ? bq.y : 0.f);
                xm.w = pk2(mm[6] ? bq.z : 0.f, mm[7] ? bq.w : 0.f);
                xk.x = (mm[0] ? 0x3F80u : 0u) | (mm[1] ? 0x3F800000u : 0u);
                xk.y = (mm[2] ? 0x3F80u : 0u) | (mm[3] ? 0x3F800000u : 0u);
                xk.z = (mm[4] ? 0x3F80u : 0u) | (mm[5] ? 0x3F800000u : 0u);
                xk.w = (mm[6] ? 0x3F80u : 0u) | (mm[7] ? 0x3F800000u : 0u);
                *(uint4*)&XH[r][wq * 8]      = xm;
                *(uint4*)&XH[r][32 + wq * 8] = xk;
            }
        } else {
            // target one-hot (64..71) + shared (72..103) + pad (104..127)
            unsigned long long lamB = cvs[bl][l >> 3] >> (8 * (l & 7));
            int lam = (int)(lamB & 7);
            int tf  = (int)(lamB >> 3) & 1;
            union { uint4 u; unsigned short s[8]; } tv;
            #pragma unroll
            for (int kk = 0; kk < 8; ++kk)
                tv.s[kk] = (tf && kk == lam) ? (unsigned short)0x3F80 : (unsigned short)0;
            *(uint4*)&XH[r][64] = tv.u;
            const float4* sp = (const float4*)(z_shared + bg * 32);
            #pragma unroll
            for (int q = 0; q < 4; ++q) {
                float4 a = sp[2 * q], b = sp[2 * q + 1];
                *(uint4*)&XH[r][72 + 8 * q] =
                    make_uint4(pk2(a.x, a.y), pk2(a.z, a.w), pk2(b.x, b.y), pk2(b.z, b.w));
            }
            uint4 zz = make_uint4(0u, 0u, 0u, 0u);
            *(uint4*)&XH[r][104] = zz;
            *(uint4*)&XH[r][112] = zz;
            *(uint4*)&XH[r][120] = zz;
        }
    }
    __syncthreads();  // B1

    // ================= GEMM1: D[c][row] = W1 * X^T =================
    f32x4 accr[4][4];
    #pragma unroll
    for (int a = 0; a < 4; ++a)
        #pragma unroll
        for (int bq = 0; bq < 4; ++bq) accr[a][bq] = (f32x4){0.f, 0.f, 0.f, 0.f};
    {
        bf16x8 wfr[4];
        #pragma unroll
        for (int mt = 0; mt < 4; ++mt) wfr[mt] = ld_frag(w1s + (mt * 4 + 0) * 512);
        #pragma unroll
        for (int ks = 0; ks < 4; ++ks) {
            bf16x8 bfr[4];
            #pragma unroll
            for (int nt = 0; nt < 4; ++nt)
                bfr[nt] = ld_frag(&XH[16 * (4 * wn + nt) + lo][ks * 32 + hi * 8]);
            bf16x8 wnx[4];
            if (ks < 3) {
                #pragma unroll
                for (int mt = 0; mt < 4; ++mt)
                    wnx[mt] = ld_frag(w1s + (mt * 4 + ks + 1) * 512);
            }
            #pragma unroll
            for (int mt = 0; mt < 4; ++mt)
                #pragma unroll
                for (int nt = 0; nt < 4; ++nt)
                    accr[mt][nt] = __builtin_amdgcn_mfma_f32_16x16x32_bf16(
                        wfr[mt], bfr[nt], accr[mt][nt], 0, 0, 0);
            if (ks < 3) {
                #pragma unroll
                for (int mt = 0; mt < 4; ++mt) wfr[mt] = wnx[mt];
            }
        }
    }

    // ---- GN1 stats (bias included) ----
    float s1[4] = {0, 0, 0, 0}, s2[4] = {0, 0, 0, 0};
    #pragma unroll
    for (int mt = 0; mt < 4; ++mt) {
        int cb = 16 * (4 * wm + mt) + 4 * hi;
        #pragma unroll
        for (int rg = 0; rg < 4; ++rg) {
            float bias = p_b1[cb + rg];
            #pragma unroll
            for (int nt = 0; nt < 4; ++nt) {
                float v = accr[mt][nt][rg] + bias;
                accr[mt][nt][rg] = v;
                s1[nt] += v; s2[nt] += v * v;
            }
        }
    }
    #pragma unroll
    for (int nt = 0; nt < 4; ++nt) {
        s1[nt] += __shfl_xor(s1[nt], 16, 64);  s1[nt] += __shfl_xor(s1[nt], 32, 64);
        s2[nt] += __shfl_xor(s2[nt], 16, 64);  s2[nt] += __shfl_xor(s2[nt], 32, 64);
    }
    if (hi == 0) {
        #pragma unroll
        for (int nt = 0; nt < 4; ++nt)
            gnA[wm][16 * (4 * wn + nt) + lo] = make_float2(s1[nt], s2[nt]);
    }
    __syncthreads();  // B2

    float mu[4], rstd[4];
    #pragma unroll
    for (int nt = 0; nt < 4; ++nt) {
        float2 a0 = gnA[0][16 * (4 * wn + nt) + lo];
        float2 a1 = gnA[1][16 * (4 * wn + nt) + lo];
        float m_  = (a0.x + a1.x) * inv128;
        float var = (a0.y + a1.y) * inv128 - m_ * m_;
        mu[nt] = m_;  rstd[nt] = rsqrtf(var + 1e-5f);
    }
    // ---- normalize + SiLU -> H ----
    #pragma unroll
    for (int mt = 0; mt < 4; ++mt) {
        int cb = 16 * (4 * wm + mt) + 4 * hi;
        #pragma unroll
        for (int nt = 0; nt < 4; ++nt) {
            int n = 16 * (4 * wn + nt) + lo;
            float sl[4];
            #pragma unroll
            for (int rg = 0; rg < 4; ++rg) {
                int c = cb + rg;
                float x = (accr[mt][nt][rg] - mu[nt]) * rstd[nt] * p_g1w[c] + p_g1b[c];
                sl[rg]  = __fdividef(x, 1.0f + __expf(-x));
            }
            *(uint2*)&XH[n][cb] = make_uint2(pk2(sl[0], sl[1]), pk2(sl[2], sl[3]));
        }
    }
    __syncthreads();  // B3

    // ================= GEMM2: D[c][row] = W2 * H^T =================
    #pragma unroll
    for (int a = 0; a < 4; ++a)
        #pragma unroll
        for (int bq = 0; bq < 4; ++bq) accr[a][bq] = (f32x4){0.f, 0.f, 0.f, 0.f};
    {
        bf16x8 wfr[4];
        #pragma unroll
        for (int mt = 0; mt < 4; ++mt) wfr[mt] = ld_frag(w2s + (mt * 4 + 0) * 512);
        #pragma unroll
        for (int ks = 0; ks < 4; ++ks) {
            bf16x8 bfr[4];
            #pragma unroll
            for (int nt = 0; nt < 4; ++nt)
                bfr[nt] = ld_frag(&XH[16 * (4 * wn + nt) + lo][ks * 32 + hi * 8]);
            bf16x8 wnx[4];
            if (ks < 3) {
                #pragma unroll
                for (int mt = 0; mt < 4; ++mt)
                    wnx[mt] = ld_frag(w2s + (mt * 4 + ks + 1) * 512);
            }
            #pragma unroll
            for (int mt = 0; mt < 4; ++mt)
                #pragma unroll
                for (int nt = 0; nt < 4; ++nt)
                    accr[mt][nt] = __builtin_amdgcn_mfma_f32_16x16x32_bf16(
                        wfr[mt], bfr[nt], accr[mt][nt], 0, 0, 0);
            if (ks < 3) {
                #pragma unroll
                for (int mt = 0; mt < 4; ++mt) wfr[mt] = wnx[mt];
            }
        }
    }

    // ---- GN2 stats ----
    float t1[4] = {0, 0, 0, 0}, t2[4] = {0, 0, 0, 0};
    #pragma unroll
    for (int mt = 0; mt < 4; ++mt) {
        int cb = 16 * (4 * wm + mt) + 4 * hi;
        #pragma unroll
        for (int rg = 0; rg < 4; ++rg) {
            float bias = p_b2[cb + rg];
            #pragma unroll
            for (int nt = 0; nt < 4; ++nt) {
                float v = accr[mt][nt][rg] + bias;
                accr[mt][nt][rg] = v;
                t1[nt] += v; t2[nt] += v * v;
            }
        }
    }
    #pragma unroll
    for (int nt = 0; nt < 4; ++nt) {
        t1[nt] += __shfl_xor(t1[nt], 16, 64);  t1[nt] += __shfl_xor(t1[nt], 32, 64);
        t2[nt] += __shfl_xor(t2[nt], 16, 64);  t2[nt] += __shfl_xor(t2[nt], 32, 64);
    }
    if (hi == 0) {
        #pragma unroll
        for (int nt = 0; nt < 4; ++nt)
            gnA[wm][16 * (4 * wn + nt) + lo] = make_float2(t1[nt], t2[nt]);
    }
    __syncthreads();  // B4

    // ---- normalize + SiLU + 128->2 dot partials ----
    float pmp[4] = {0, 0, 0, 0}, plp[4] = {0, 0, 0, 0};
    float mu2[4], rstd2[4];
    #pragma unroll
    for (int nt = 0; nt < 4; ++nt) {
        float2 a0 = gnA[0][16 * (4 * wn + nt) + lo];
        float2 a1 = gnA[1][16 * (4 * wn + nt) + lo];
        float m_  = (a0.x + a1.x) * inv128;
        float var = (a0.y + a1.y) * inv128 - m_ * m_;
        mu2[nt] = m_;  rstd2[nt] = rsqrtf(var + 1e-5f);
    }
    #pragma unroll
    for (int mt = 0; mt < 4; ++mt) {
        int cb = 16 * (4 * wm + mt) + 4 * hi;
        #pragma unroll
        for (int rg = 0; rg < 4; ++rg) {
            int c = cb + rg;
            float wg = p_g2w[c], bgn = p_g2b[c], w30 = p_w3[0][c], w31 = p_w3[1][c];
            #pragma unroll
            for (int nt = 0; nt < 4; ++nt) {
                float x  = (accr[mt][nt][rg] - mu2[nt]) * rstd2[nt] * wg + bgn;
                float sl = __fdividef(x, 1.0f + __expf(-x));
                pmp[nt] += sl * w30;
                plp[nt] += sl * w31;
            }
        }
    }
    #pragma unroll
    for (int nt = 0; nt < 4; ++nt) {
        pmp[nt] += __shfl_xor(pmp[nt], 16, 64);  pmp[nt] += __shfl_xor(pmp[nt], 32, 64);
        plp[nt] += __shfl_xor(plp[nt], 16, 64);  plp[nt] += __shfl_xor(plp[nt], 32, 64);
    }
    if (hi == 0) {
        #pragma unroll
        for (int nt = 0; nt < 4; ++nt)
            gnB[wm][16 * (4 * wn + nt) + lo] = make_float2(pmp[nt], plp[nt]);
    }
    __syncthreads();  // B5

    // ---- tanh-scale + KLD + mean over g + accumulate ----
    if (wm == 0 && hi == 0) {
        float sc0 = __expf(p_ts[0]), sc1 = __expf(p_ts[1]);
        #pragma unroll
        for (int nt = 0; nt < 4; ++nt) {
            int n = 16 * (4 * wn + nt) + lo;       // row in [0,128)
            float2 q0 = gnB[0][n], q1 = gnB[1][n];
            float pm = q0.x + q1.x + p_b3[0];
            float pl = q0.y + q1.y + p_b3[1];
            pm = tanhf(pm / sc0) * sc0;
            pl = tanhf(pl / sc1) * sc1;
            int bg = grp * 16 + (n >> 3);
            float zm = z_mean[bg * 32 + l];
            float zl = z_logstd[bg * 32 + l];
            float vq = __expf(2.0f * zl);
            float d  = zm - pm;
            float kld = pl - zl + (vq + d * d) * 0.5f * __expf(-2.0f * pl) - 0.5f;
            kld += __shfl_xor(kld, 1, 64);
            kld += __shfl_xor(kld, 2, 64);
            kld += __shfl_xor(kld, 4, 64);
            if ((lo & 7) == 0) atomicAdd(&out[bg], kld * 0.125f);
        }
    }
}

extern "C" void kernel_launch(void* const* d_in, const int* in_sizes, int n_in,
                              void* d_out, int out_size, void* d_ws, size_t ws_size,
                              hipStream_t stream) {
    const float* z_sample      = (const float*)d_in[0];
    const int*   target        = (const int*)d_in[1];
    const float* z_mean        = (const float*)d_in[2];
    const float* z_logstd      = (const float*)d_in[3];
    const float* z_shared      = (const float*)d_in[4];
    const float* u_gumbel      = (const float*)d_in[5];
    const float* u_adj         = (const float*)d_in[6];
    const float* target_params = (const float*)d_in[7];
    const float* enco_theta    = (const float*)d_in[8];
    const float* enco_gamma    = (const float*)d_in[9];
    const float* W1            = (const float*)d_in[10];
    const float* pb1           = (const float*)d_in[11];
    const float* g1w           = (const float*)d_in[12];
    const float* g1b           = (const float*)d_in[13];
    const float* W2            = (const float*)d_in[14];
    const float* pb2           = (const float*)d_in[15];
    const float* g2w           = (const float*)d_in[16];
    const float* g2b           = (const float*)d_in[17];
    const float* W3            = (const float*)d_in[18];
    const float* pb3           = (const float*)d_in[19];
    const float* tsc           = (const float*)d_in[20];

    unsigned char* cvarpk = (unsigned char*)d_ws;                          // 32 KB
    unsigned int*  wsmask = (unsigned int*)((char*)d_ws + 32768);          // 1 MB
    unsigned short* wscr  = (unsigned short*)((char*)d_ws + 32768 + 1048576); // 2 MB

    prep_kernel<<<1536, 256, 0, stream>>>(u_gumbel, u_adj, target_params,
                                          enco_theta, enco_gamma, target,
                                          W1, W2, (float*)d_out,
                                          cvarpk, wsmask, wscr);
    fused_kernel<<<2048, 256, 0, stream>>>(z_sample, z_mean, z_logstd, z_shared,
                                           pb1, g1w, g1b, pb2, g2w, g2b,
                                           W3, pb3, tsc, wscr, cvarpk, wsmask,
                                           (float*)d_out);
}

// Round 7
// 175.059 us; speedup vs baseline: 1.2539x; 1.0284x over previous
//
#include <hip/hip_runtime.h>
#include <hip/hip_bf16.h>

// Problem constants
#define B_DIM 1024
#define L_DIM 32
#define K_DIM 8
#define G_DIM 8
#define C_DIM 128
#define S_DIM 32
#define DIN   104   // 2L + K + S

typedef __bf16  bf16x8 __attribute__((ext_vector_type(8)));
typedef float   f32x4  __attribute__((ext_vector_type(4)));

union frag_u { uint4 u; bf16x8 v; };

static __device__ __forceinline__ unsigned int pk2(float a, float b) {
    __hip_bfloat162 h = __float22bfloat162_rn(make_float2(a, b));  // v_cvt_pk_bf16_f32
    union { __hip_bfloat162 h; unsigned int u; } v; v.h = h; return v.u;
}
static __device__ __forceinline__ bf16x8 ld_frag(const unsigned short* p) {
    frag_u t; t.u = *(const uint4*)p; return t.v;
}
static __device__ __forceinline__ bf16x8 u2f(uint4 u) {
    frag_u t; t.u = u; return t.v;
}
static __device__ __forceinline__ float siluf(float x) {
    return __fdividef(x, 1.0f + __expf(-x));
}

// ---------------------------------------------------------------------------
// Kernel 1 (merged): blocks [0,1024): per-b decisions (fp64) -> cvarpk byte +
//   precomputed parent-mask bits wsmask[l][b][g]; zero d_out[b].
//   blocks [1024,1536): W1/W2 fp32->bf16 fragment repack.
// ---------------------------------------------------------------------------
__global__ __launch_bounds__(256) void prep_kernel(
    const float* __restrict__ u_gumbel,      // [B,L,K]
    const float* __restrict__ u_adj,         // [B,G,K,K]
    const float* __restrict__ target_params, // [L,K]
    const float* __restrict__ enco_theta,    // [K,K]
    const float* __restrict__ enco_gamma,    // [K,K]
    const int*   __restrict__ target,        // [B]
    const float* __restrict__ W1,            // [32][128][104]
    const float* __restrict__ W2,            // [32][128][128]
    float*       __restrict__ out,           // [B] (zeroed here, atomics later)
    unsigned char* __restrict__ cvarpk,      // [B][32]  cvar | tflag<<3
    unsigned int*  __restrict__ wsmask,      // [L][B][G] parent-mask bits over j
    unsigned short* __restrict__ wscr)       // bf16 frag-ordered weights
{
    const int t = threadIdx.x;
    if (blockIdx.x >= 1024) {
        // ---- weight repack: frag F = (which*32+l)*32 + cb*4 + ks ----
        int gtid  = (blockIdx.x - 1024) * 256 + t;   // [0, 131072)
        int lane  = gtid & 63;
        int ks    = (gtid >> 6) & 3;
        int mt    = (gtid >> 8) & 3;
        int wm    = (gtid >> 10) & 1;
        int l     = (gtid >> 11) & 31;
        int which = gtid >> 16;
        int m  = 16 * (4 * wm + mt) + (lane & 15);
        int k0 = ks * 32 + (lane >> 4) * 8;
        uint4 o;
        if (which == 0) {
            if (k0 >= 104) {
                o = make_uint4(0u, 0u, 0u, 0u);
            } else {
                const float* p = W1 + (size_t)l * 13312 + m * 104 + k0;
                float4 a = *(const float4*)p, bq = *(const float4*)(p + 4);
                o = make_uint4(pk2(a.x, a.y), pk2(a.z, a.w), pk2(bq.x, bq.y), pk2(bq.z, bq.w));
            }
        } else {
            const float* p = W2 + (size_t)l * 16384 + m * 128 + k0;
            float4 a = *(const float4*)p, bq = *(const float4*)(p + 4);
            o = make_uint4(pk2(a.x, a.y), pk2(a.z, a.w), pk2(bq.x, bq.y), pk2(bq.z, bq.w));
        }
        *(uint4*)(wscr + (size_t)gtid * 8) = o;
        return;
    }

    __shared__ double ep[64];
    __shared__ unsigned char cv8[32];
    __shared__ unsigned long long adjb[8];
    const int b = blockIdx.x;
    if (t < 64) {
        double th = (double)enco_theta[t];
        double ga = (double)enco_gamma[t];
        ep[t] = (1.0 / (1.0 + exp(-th))) * (1.0 / (1.0 + exp(-ga)));
    }
    if (t == 0) out[b] = 0.0f;
    __syncthreads();

    // gumbel argmax: thread t = l*8 + k; 8-lane subgroup reduction
    {
        const int l = t >> 3, k = t & 7;
        double u = (double)u_gumbel[b * 256 + t];
        double g = -log(-log(u + 1e-10) + 1e-10);
        double v = (double)target_params[t] + g;   // TAU = 1
        int bk = k;
        #pragma unroll
        for (int off = 1; off < 8; off <<= 1) {
            double ov = __shfl_xor(v, off, 64);
            int   obk = __shfl_xor(bk, off, 64);
            if (ov > v || (ov == v && obk < bk)) { v = ov; bk = obk; }
        }
        if (k == 0) {
            int tg = target[b];
            unsigned char pkd = (unsigned char)(bk | ((bk == tg) ? 8 : 0));
            cvarpk[b * 32 + l] = pkd;
            cv8[l] = pkd;
        }
    }
    // adjacency: wave w handles g = w and g = w+4; bits into LDS only
    {
        const int wv = t >> 6, lane = t & 63;
        #pragma unroll
        for (int q = 0; q < 2; ++q) {
            int gg = wv + 4 * q;
            double u = (double)u_adj[b * 512 + gg * 64 + lane];
            unsigned long long m = __ballot(u < ep[lane]);
            if (lane == 0) adjb[gg] = m;
        }
    }
    __syncthreads();

    // parent-mask: thread (g = t>>5, l = t&31): bit j = adj[g][cvar_j][cvar_l], j!=l
    {
        const int g = t >> 5, l = t & 31;
        int lam = cv8[l] & 7;
        unsigned long long bits = adjb[g] >> lam;   // bit (kap*8) now selects
        unsigned int mask = 0u;
        #pragma unroll
        for (int j = 0; j < 32; ++j) {
            int kap = cv8[j] & 7;
            mask |= ((unsigned int)(bits >> (kap * 8)) & 1u) << j;
        }
        mask &= ~(1u << l);
        wsmask[l * 8192 + b * 8 + g] = mask;
    }
}

// ---------------------------------------------------------------------------
// Kernel 2: fully wave-autonomous fused pipeline.
// Grid 2048: blockIdx = grp*32 + l  (same-l -> same XCD -> weights L2-resident).
// Block = 4 waves x 32 rows = 128 rows = 16 batches x 8 graphs.
// Per wave (rows r = w*32 + nt*16 + lo, nt in {0,1}):
//   build X B-frags IN REGISTERS -> GEMM1 (W1 streamed from L2 scratch) ->
//   GN1 stats via in-wave shuffles -> SiLU -> H into wave-PRIVATE LDS slice ->
//   GEMM2 -> GN2 + 128->2 dot in-wave -> tanh/KLD -> atomicAdd out[bg].
// ONE __syncthreads total (param staging). No inter-wave dependencies.
// ---------------------------------------------------------------------------
__global__ __launch_bounds__(256, 2) void fused_kernel(
    const float* __restrict__ z_sample,   // [B,32]
    const float* __restrict__ z_mean,     // [B,32]
    const float* __restrict__ z_logstd,   // [B,32]
    const float* __restrict__ z_shared,   // [B,32]
    const float* __restrict__ pb1,        // [32][128]
    const float* __restrict__ g1w,
    const float* __restrict__ g1b,
    const float* __restrict__ pb2,
    const float* __restrict__ g2w,
    const float* __restrict__ g2b,
    const float* __restrict__ W3,         // [32][2][128]
    const float* __restrict__ pb3,        // [32][2]
    const float* __restrict__ tsc,        // [32][2]
    const unsigned short* __restrict__ wscr,    // bf16 frag-ordered weights
    const unsigned char*  __restrict__ cvarpk,  // [B][32]
    const unsigned int*   __restrict__ wsmask,  // [L][B][G]
    float* __restrict__ out)                    // [B]
{
    __shared__ __align__(16) unsigned short XH[4][32][136];  // wave-private H slices
    __shared__ float p_g1w[128], p_g1b[128], p_b1[128];
    __shared__ float p_g2w[128], p_g2b[128], p_b2[128];
    __shared__ float p_w3[2][128];
    __shared__ float p_b3[2], p_ts[2];
    __shared__ unsigned int  msk[128];     // [b_loc*8+g]
    __shared__ unsigned char cvl[16];      // cvar|tflag byte per b_loc

    const int tid  = threadIdx.x;
    const int w    = tid >> 6, lane = tid & 63;
    const int lo   = lane & 15, hi = lane >> 4;
    const int l    = blockIdx.x & 31;
    const int grp  = blockIdx.x >> 5;

    // ---- stage per-latent params + per-block decisions (ONLY barrier) ----
    if (tid < 128) {
        int c = tid;
        p_g1w[c] = g1w[l * 128 + c];  p_g1b[c] = g1b[l * 128 + c];
        p_b1[c]  = pb1[l * 128 + c];  p_w3[0][c] = W3[l * 256 + c];
        msk[c]   = wsmask[l * 8192 + grp * 128 + c];
    } else {
        int c = tid - 128;
        p_g2w[c] = g2w[l * 128 + c];  p_g2b[c] = g2b[l * 128 + c];
        p_b2[c]  = pb2[l * 128 + c];  p_w3[1][c] = W3[l * 256 + 128 + c];
    }
    if (tid < 16) cvl[tid] = cvarpk[(size_t)(grp * 16 + tid) * 32 + l];
    if (tid == 0) {
        p_b3[0] = pb3[l * 2];  p_b3[1] = pb3[l * 2 + 1];
        p_ts[0] = tsc[l * 2];  p_ts[1] = tsc[l * 2 + 1];
    }
    __syncthreads();  // B0 — the only barrier

    // ================= build X B-frags in registers =================
    // frag[nt][ks]: B[row = w*32+nt*16+lo][k = ks*32 + hi*8 + j]
    bf16x8 bq[2][4];
    #pragma unroll
    for (int nt = 0; nt < 2; ++nt) {
        int r  = w * 32 + nt * 16 + lo;
        int bl = r >> 3;
        int bg = grp * 16 + bl;
        unsigned int m32 = msk[r];
        unsigned int mq  = (m32 >> (hi * 8)) & 0xffu;
        const float4* zp = (const float4*)(z_sample + bg * 32 + hi * 8);
        float4 za = zp[0], zb = zp[1];
        uint4 f0;   // masked z (cols hi*8..+7)
        f0.x = pk2((mq & 1u)   ? za.x : 0.f, (mq & 2u)   ? za.y : 0.f);
        f0.y = pk2((mq & 4u)   ? za.z : 0.f, (mq & 8u)   ? za.w : 0.f);
        f0.z = pk2((mq & 16u)  ? zb.x : 0.f, (mq & 32u)  ? zb.y : 0.f);
        f0.w = pk2((mq & 64u)  ? zb.z : 0.f, (mq & 128u) ? zb.w : 0.f);
        uint4 f1;   // mask indicator as bf16 1.0
        f1.x = ((mq & 1u)   ? 0x3F80u : 0u) | ((mq & 2u)   ? 0x3F800000u : 0u);
        f1.y = ((mq & 4u)   ? 0x3F80u : 0u) | ((mq & 8u)   ? 0x3F800000u : 0u);
        f1.z = ((mq & 16u)  ? 0x3F80u : 0u) | ((mq & 32u)  ? 0x3F800000u : 0u);
        f1.w = ((mq & 64u)  ? 0x3F80u : 0u) | ((mq & 128u) ? 0x3F800000u : 0u);
        // frag2/frag3: [t one-hot (8) | z_shared (32) | pad (24)]
        unsigned int cb8 = cvl[bl];
        int lam = cb8 & 7, tf = (cb8 >> 3) & 1;
        int zsb = (hi == 0) ? 24 : (hi - 1) * 8;
        const float4* sp = (const float4*)(z_shared + bg * 32 + zsb);
        float4 sa = sp[0], sb = sp[1];
        uint4 fz;
        fz.x = pk2(sa.x, sa.y); fz.y = pk2(sa.z, sa.w);
        fz.z = pk2(sb.x, sb.y); fz.w = pk2(sb.z, sb.w);
        unsigned int ohw = tf ? (0x3F80u << ((lam & 1) << 4)) : 0u;
        int lq = lam >> 1;
        uint4 fo;
        fo.x = (lq == 0) ? ohw : 0u;
        fo.y = (lq == 1) ? ohw : 0u;
        fo.z = (lq == 2) ? ohw : 0u;
        fo.w = (lq == 3) ? ohw : 0u;
        bool h0 = (hi == 0);
        uint4 f2, f3;
        f2.x = h0 ? fo.x : fz.x;  f2.y = h0 ? fo.y : fz.y;
        f2.z = h0 ? fo.z : fz.z;  f2.w = h0 ? fo.w : fz.w;
        f3.x = h0 ? fz.x : 0u;    f3.y = h0 ? fz.y : 0u;
        f3.z = h0 ? fz.z : 0u;    f3.w = h0 ? fz.w : 0u;
        bq[nt][0] = u2f(f0); bq[nt][1] = u2f(f1);
        bq[nt][2] = u2f(f2); bq[nt][3] = u2f(f3);
    }

    const float inv128 = 1.0f / 128.0f;

    // ================= GEMM1: D[c][row] = W1 * X^T =================
    f32x4 acc[8][2];
    #pragma unroll
    for (int cb = 0; cb < 8; ++cb)
        #pragma unroll
        for (int nt = 0; nt < 2; ++nt) acc[cb][nt] = (f32x4){0.f, 0.f, 0.f, 0.f};
    {
        const unsigned short* w1p = wscr + (size_t)(l * 32) * 512 + lane * 8;
        #pragma unroll
        for (int ks = 0; ks < 4; ++ks) {
            bf16x8 wf[8];
            #pragma unroll
            for (int cb = 0; cb < 8; ++cb) wf[cb] = ld_frag(w1p + (cb * 4 + ks) * 512);
            #pragma unroll
            for (int cb = 0; cb < 8; ++cb)
                #pragma unroll
                for (int nt = 0; nt < 2; ++nt)
                    acc[cb][nt] = __builtin_amdgcn_mfma_f32_16x16x32_bf16(
                        wf[cb], bq[nt][ks], acc[cb][nt], 0, 0, 0);
        }
    }

    // ---- GN1: stats fully in-wave (sum over c = in-lane + shfl over hi) ----
    float s1[2] = {0.f, 0.f}, s2[2] = {0.f, 0.f};
    #pragma unroll
    for (int cb = 0; cb < 8; ++cb) {
        float4 b4 = *(const float4*)&p_b1[cb * 16 + hi * 4];
        #pragma unroll
        for (int rg = 0; rg < 4; ++rg) {
            float bias = ((const float*)&b4)[rg];
            #pragma unroll
            for (int nt = 0; nt < 2; ++nt) {
                float v = acc[cb][nt][rg] + bias;
                acc[cb][nt][rg] = v;
                s1[nt] += v;  s2[nt] += v * v;
            }
        }
    }
    float mu[2], rstd[2];
    #pragma unroll
    for (int nt = 0; nt < 2; ++nt) {
        s1[nt] += __shfl_xor(s1[nt], 16, 64);  s1[nt] += __shfl_xor(s1[nt], 32, 64);
        s2[nt] += __shfl_xor(s2[nt], 16, 64);  s2[nt] += __shfl_xor(s2[nt], 32, 64);
        float m_  = s1[nt] * inv128;
        float var = s2[nt] * inv128 - m_ * m_;
        mu[nt] = m_;  rstd[nt] = rsqrtf(var + 1e-5f);
    }
    // ---- normalize + SiLU -> wave-private H slice ----
    #pragma unroll
    for (int cb = 0; cb < 8; ++cb) {
        float4 gw4 = *(const float4*)&p_g1w[cb * 16 + hi * 4];
        float4 gb4 = *(const float4*)&p_g1b[cb * 16 + hi * 4];
        #pragma unroll
        for (int nt = 0; nt < 2; ++nt) {
            float sl[4];
            #pragma unroll
            for (int rg = 0; rg < 4; ++rg) {
                float x = (acc[cb][nt][rg] - mu[nt]) * rstd[nt] * ((const float*)&gw4)[rg]
                          + ((const float*)&gb4)[rg];
                sl[rg] = siluf(x);
            }
            *(uint2*)&XH[w][nt * 16 + lo][cb * 16 + hi * 4] =
                make_uint2(pk2(sl[0], sl[1]), pk2(sl[2], sl[3]));
        }
    }
    // (in-wave LDS RAW: compiler orders via lgkmcnt — no barrier needed)

    // ================= GEMM2: D[c][row] = W2 * H^T =================
    #pragma unroll
    for (int cb = 0; cb < 8; ++cb)
        #pragma unroll
        for (int nt = 0; nt < 2; ++nt) acc[cb][nt] = (f32x4){0.f, 0.f, 0.f, 0.f};
    {
        const unsigned short* w2p = wscr + (size_t)((32 + l) * 32) * 512 + lane * 8;
        #pragma unroll
        for (int ks = 0; ks < 4; ++ks) {
            bf16x8 wf[8];
            #pragma unroll
            for (int cb = 0; cb < 8; ++cb) wf[cb] = ld_frag(w2p + (cb * 4 + ks) * 512);
            bf16x8 bf0 = ld_frag(&XH[w][lo][ks * 32 + hi * 8]);
            bf16x8 bf1 = ld_frag(&XH[w][16 + lo][ks * 32 + hi * 8]);
            #pragma unroll
            for (int cb = 0; cb < 8; ++cb) {
                acc[cb][0] = __builtin_amdgcn_mfma_f32_16x16x32_bf16(
                    wf[cb], bf0, acc[cb][0], 0, 0, 0);
                acc[cb][1] = __builtin_amdgcn_mfma_f32_16x16x32_bf16(
                    wf[cb], bf1, acc[cb][1], 0, 0, 0);
            }
        }
    }

    // ---- GN2 stats in-wave ----
    float t1[2] = {0.f, 0.f}, t2[2] = {0.f, 0.f};
    #pragma unroll
    for (int cb = 0; cb < 8; ++cb) {
        float4 b4 = *(const float4*)&p_b2[cb * 16 + hi * 4];
        #pragma unroll
        for (int rg = 0; rg < 4; ++rg) {
            float bias = ((const float*)&b4)[rg];
            #pragma unroll
            for (int nt = 0; nt < 2; ++nt) {
                float v = acc[cb][nt][rg] + bias;
                acc[cb][nt][rg] = v;
                t1[nt] += v;  t2[nt] += v * v;
            }
        }
    }
    float mu2[2], rstd2[2];
    #pragma unroll
    for (int nt = 0; nt < 2; ++nt) {
        t1[nt] += __shfl_xor(t1[nt], 16, 64);  t1[nt] += __shfl_xor(t1[nt], 32, 64);
        t2[nt] += __shfl_xor(t2[nt], 16, 64);  t2[nt] += __shfl_xor(t2[nt], 32, 64);
        float m_  = t1[nt] * inv128;
        float var = t2[nt] * inv128 - m_ * m_;
        mu2[nt] = m_;  rstd2[nt] = rsqrtf(var + 1e-5f);
    }
    // ---- normalize + SiLU + 128->2 dot, in-wave ----
    float pmp[2] = {0.f, 0.f}, plp[2] = {0.f, 0.f};
    #pragma unroll
    for (int cb = 0; cb < 8; ++cb) {
        float4 gw4 = *(const float4*)&p_g2w[cb * 16 + hi * 4];
        float4 gb4 = *(const float4*)&p_g2b[cb * 16 + hi * 4];
        float4 w04 = *(const float4*)&p_w3[0][cb * 16 + hi * 4];
        float4 w14 = *(const float4*)&p_w3[1][cb * 16 + hi * 4];
        #pragma unroll
        for (int rg = 0; rg < 4; ++rg) {
            float wg = ((const float*)&gw4)[rg], gb = ((const float*)&gb4)[rg];
            float w0 = ((const float*)&w04)[rg], w1 = ((const float*)&w14)[rg];
            #pragma unroll
            for (int nt = 0; nt < 2; ++nt) {
                float x  = (acc[cb][nt][rg] - mu2[nt]) * rstd2[nt] * wg + gb;
                float sl = siluf(x);
                pmp[nt] += sl * w0;
                plp[nt] += sl * w1;
            }
        }
    }
    #pragma unroll
    for (int nt = 0; nt < 2; ++nt) {
        pmp[nt] += __shfl_xor(pmp[nt], 16, 64);  pmp[nt] += __shfl_xor(pmp[nt], 32, 64);
        plp[nt] += __shfl_xor(plp[nt], 16, 64);  plp[nt] += __shfl_xor(plp[nt], 32, 64);
    }

    // ---- tanh-scale + KLD + mean over g + accumulate (computed on all lanes,
    //      shuffles stay valid; atomic predicated to 4 lanes) ----
    {
        float sc0 = __expf(p_ts[0]), sc1 = __expf(p_ts[1]);
        float is0 = __expf(-p_ts[0]), is1 = __expf(-p_ts[1]);
        #pragma unroll
        for (int nt = 0; nt < 2; ++nt) {
            float pm = pmp[nt] + p_b3[0];
            float pl = plp[nt] + p_b3[1];
            // tanh(x) = 1 - 2/(e^{2x}+1)  (inf-safe)
            float e0 = __expf(2.0f * pm * is0);
            pm = (1.0f - 2.0f * __fdividef(1.0f, e0 + 1.0f)) * sc0;
            float e1 = __expf(2.0f * pl * is1);
            pl = (1.0f - 2.0f * __fdividef(1.0f, e1 + 1.0f)) * sc1;
            int r  = w * 32 + nt * 16 + lo;
            int bg = grp * 16 + (r >> 3);
            float zm = z_mean[bg * 32 + l];
            float zl = z_logstd[bg * 32 + l];
            float vq = __expf(2.0f * zl);
            float d  = zm - pm;
            float kld = pl - zl + (vq + d * d) * 0.5f * __expf(-2.0f * pl) - 0.5f;
            kld += __shfl_xor(kld, 1, 64);
            kld += __shfl_xor(kld, 2, 64);
            kld += __shfl_xor(kld, 4, 64);
            if (hi == 0 && (lo & 7) == 0) atomicAdd(&out[bg], kld * 0.125f);
        }
    }
}

extern "C" void kernel_launch(void* const* d_in, const int* in_sizes, int n_in,
                              void* d_out, int out_size, void* d_ws, size_t ws_size,
                              hipStream_t stream) {
    const float* z_sample      = (const float*)d_in[0];
    const int*   target        = (const int*)d_in[1];
    const float* z_mean        = (const float*)d_in[2];
    const float* z_logstd      = (const float*)d_in[3];
    const float* z_shared      = (const float*)d_in[4];
    const float* u_gumbel      = (const float*)d_in[5];
    const float* u_adj         = (const float*)d_in[6];
    const float* target_params = (const float*)d_in[7];
    const float* enco_theta    = (const float*)d_in[8];
    const float* enco_gamma    = (const float*)d_in[9];
    const float* W1            = (const float*)d_in[10];
    const float* pb1           = (const float*)d_in[11];
    const float* g1w           = (const float*)d_in[12];
    const float* g1b           = (const float*)d_in[13];
    const float* W2            = (const float*)d_in[14];
    const float* pb2           = (const float*)d_in[15];
    const float* g2w           = (const float*)d_in[16];
    const float* g2b           = (const float*)d_in[17];
    const float* W3            = (const float*)d_in[18];
    const float* pb3           = (const float*)d_in[19];
    const float* tsc           = (const float*)d_in[20];

    unsigned char* cvarpk = (unsigned char*)d_ws;                          // 32 KB
    unsigned int*  wsmask = (unsigned int*)((char*)d_ws + 32768);          // 1 MB
    unsigned short* wscr  = (unsigned short*)((char*)d_ws + 32768 + 1048576); // 2 MB

    prep_kernel<<<1536, 256, 0, stream>>>(u_gumbel, u_adj, target_params,
                                          enco_theta, enco_gamma, target,
                                          W1, W2, (float*)d_out,
                                          cvarpk, wsmask, wscr);
    fused_kernel<<<2048, 256, 0, stream>>>(z_sample, z_mean, z_logstd, z_shared,
                                           pb1, g1w, g1b, pb2, g2w, g2b,
                                           W3, pb3, tsc, wscr, cvarpk, wsmask,
                                           (float*)d_out);
}

// Round 8
// 169.839 us; speedup vs baseline: 1.2924x; 1.0307x over previous
//
#include <hip/hip_runtime.h>
#include <hip/hip_bf16.h>

// Problem constants
#define B_DIM 1024
#define L_DIM 32
#define K_DIM 8
#define G_DIM 8
#define C_DIM 128
#define S_DIM 32
#define DIN   104   // 2L + K + S

typedef __bf16  bf16x8 __attribute__((ext_vector_type(8)));
typedef float   f32x4  __attribute__((ext_vector_type(4)));

union frag_u { uint4 u; bf16x8 v; };

static __device__ __forceinline__ unsigned int pk2(float a, float b) {
    __hip_bfloat162 h = __float22bfloat162_rn(make_float2(a, b));  // v_cvt_pk_bf16_f32
    union { __hip_bfloat162 h; unsigned int u; } v; v.h = h; return v.u;
}
static __device__ __forceinline__ bf16x8 ld_frag(const unsigned short* p) {
    frag_u t; t.u = *(const uint4*)p; return t.v;
}
static __device__ __forceinline__ bf16x8 u2f(uint4 u) {
    frag_u t; t.u = u; return t.v;
}
static __device__ __forceinline__ float siluf(float x) {
    return __fdividef(x, 1.0f + __expf(-x));
}

// ---------------------------------------------------------------------------
// Kernel 1 (merged): blocks [0,1024): per-b decisions -> cvarpk byte +
//   parent-mask bits wsmask[l][b][g]; zero d_out[b]. Gumbel argmax uses an
//   fp32 fast path; falls back to fp64 (exact vs reference) only when the
//   top-2 gap < 1e-3 (prob ~1e-4).
//   blocks [1024,1536): W1/W2 fp32->bf16 fragment repack.
// ---------------------------------------------------------------------------
__global__ __launch_bounds__(256) void prep_kernel(
    const float* __restrict__ u_gumbel,      // [B,L,K]
    const float* __restrict__ u_adj,         // [B,G,K,K]
    const float* __restrict__ target_params, // [L,K]
    const float* __restrict__ enco_theta,    // [K,K]
    const float* __restrict__ enco_gamma,    // [K,K]
    const int*   __restrict__ target,        // [B]
    const float* __restrict__ W1,            // [32][128][104]
    const float* __restrict__ W2,            // [32][128][128]
    float*       __restrict__ out,           // [B] (zeroed here, atomics later)
    unsigned char* __restrict__ cvarpk,      // [B][32]  cvar | tflag<<3
    unsigned int*  __restrict__ wsmask,      // [L][B][G] parent-mask bits over j
    unsigned short* __restrict__ wscr)       // bf16 frag-ordered weights
{
    const int t = threadIdx.x;
    if (blockIdx.x >= 1024) {
        // ---- weight repack: frag F = (which*32+l)*32 + cb*4 + ks ----
        int gtid  = (blockIdx.x - 1024) * 256 + t;   // [0, 131072)
        int lane  = gtid & 63;
        int ks    = (gtid >> 6) & 3;
        int mt    = (gtid >> 8) & 3;
        int wm    = (gtid >> 10) & 1;
        int l     = (gtid >> 11) & 31;
        int which = gtid >> 16;
        int m  = 16 * (4 * wm + mt) + (lane & 15);
        int k0 = ks * 32 + (lane >> 4) * 8;
        uint4 o;
        if (which == 0) {
            if (k0 >= 104) {
                o = make_uint4(0u, 0u, 0u, 0u);
            } else {
                const float* p = W1 + (size_t)l * 13312 + m * 104 + k0;
                float4 a = *(const float4*)p, bq = *(const float4*)(p + 4);
                o = make_uint4(pk2(a.x, a.y), pk2(a.z, a.w), pk2(bq.x, bq.y), pk2(bq.z, bq.w));
            }
        } else {
            const float* p = W2 + (size_t)l * 16384 + m * 128 + k0;
            float4 a = *(const float4*)p, bq = *(const float4*)(p + 4);
            o = make_uint4(pk2(a.x, a.y), pk2(a.z, a.w), pk2(bq.x, bq.y), pk2(bq.z, bq.w));
        }
        *(uint4*)(wscr + (size_t)gtid * 8) = o;
        return;
    }

    __shared__ double ep[64];
    __shared__ unsigned char cv8[32];
    __shared__ unsigned long long adjb[8];
    const int b = blockIdx.x;
    if (t < 64) {
        double th = (double)enco_theta[t];
        double ga = (double)enco_gamma[t];
        ep[t] = (1.0 / (1.0 + exp(-th))) * (1.0 / (1.0 + exp(-ga)));
    }
    if (t == 0) out[b] = 0.0f;
    __syncthreads();

    // gumbel argmax: thread t = l*8 + k; fp32 fast path, fp64 fallback
    {
        const int l = t >> 3, k = t & 7;
        float uf = u_gumbel[b * 256 + t];
        float gf = -__logf(-__logf(uf + 1e-10f) + 1e-10f);
        float vf = target_params[t] + gf;
        float vm = vf; int bk = k;
        #pragma unroll
        for (int off = 1; off < 8; off <<= 1) {
            float ov = __shfl_xor(vm, off, 64);
            int  obk = __shfl_xor(bk, off, 64);
            if (ov > vm || (ov == vm && obk < bk)) { vm = ov; bk = obk; }
        }
        int amb = ((k != bk) && (vm - vf < 1e-3f)) ? 1 : 0;
        #pragma unroll
        for (int off = 1; off < 8; off <<= 1) amb |= __shfl_xor(amb, off, 64);
        if (amb) {   // group-uniform; rare
            double ud = (double)uf;
            double gd = -log(-log(ud + 1e-10) + 1e-10);
            double vd = (double)target_params[t] + gd;
            int bk2 = k;
            #pragma unroll
            for (int off = 1; off < 8; off <<= 1) {
                double ov = __shfl_xor(vd, off, 64);
                int   obk = __shfl_xor(bk2, off, 64);
                if (ov > vd || (ov == vd && obk < bk2)) { vd = ov; bk2 = obk; }
            }
            bk = bk2;
        }
        if (k == 0) {
            int tg = target[b];
            unsigned char pkd = (unsigned char)(bk | ((bk == tg) ? 8 : 0));
            cvarpk[b * 32 + l] = pkd;
            cv8[l] = pkd;
        }
    }
    // adjacency: wave w handles g = w and g = w+4; bits into LDS only
    {
        const int wv = t >> 6, lane = t & 63;
        #pragma unroll
        for (int q = 0; q < 2; ++q) {
            int gg = wv + 4 * q;
            double u = (double)u_adj[b * 512 + gg * 64 + lane];
            unsigned long long m = __ballot(u < ep[lane]);
            if (lane == 0) adjb[gg] = m;
        }
    }
    __syncthreads();

    // parent-mask: thread (g = t>>5, l = t&31): bit j = adj[g][cvar_j][cvar_l], j!=l
    {
        const int g = t >> 5, l = t & 31;
        int lam = cv8[l] & 7;
        unsigned long long bits = adjb[g] >> lam;   // bit (kap*8) now selects
        unsigned int mask = 0u;
        #pragma unroll
        for (int j = 0; j < 32; ++j) {
            int kap = cv8[j] & 7;
            mask |= ((unsigned int)(bits >> (kap * 8)) & 1u) << j;
        }
        mask &= ~(1u << l);
        wsmask[l * 8192 + b * 8 + g] = mask;
    }
}

// ---------------------------------------------------------------------------
// Kernel 2: fully wave-autonomous fused pipeline (R7 structure).
// Grid 2048: blockIdx = grp*32 + l. Block = 4 waves x 32 rows.
// (256,3): target 3 blocks/CU (~170 reg budget); weight frags loaded 4 at a
// time (wf[4]) to cut peak register demand vs R7's wf[8].
// ---------------------------------------------------------------------------
__global__ __launch_bounds__(256, 3) void fused_kernel(
    const float* __restrict__ z_sample,   // [B,32]
    const float* __restrict__ z_mean,     // [B,32]
    const float* __restrict__ z_logstd,   // [B,32]
    const float* __restrict__ z_shared,   // [B,32]
    const float* __restrict__ pb1,        // [32][128]
    const float* __restrict__ g1w,
    const float* __restrict__ g1b,
    const float* __restrict__ pb2,
    const float* __restrict__ g2w,
    const float* __restrict__ g2b,
    const float* __restrict__ W3,         // [32][2][128]
    const float* __restrict__ pb3,        // [32][2]
    const float* __restrict__ tsc,        // [32][2]
    const unsigned short* __restrict__ wscr,    // bf16 frag-ordered weights
    const unsigned char*  __restrict__ cvarpk,  // [B][32]
    const unsigned int*   __restrict__ wsmask,  // [L][B][G]
    float* __restrict__ out)                    // [B]
{
    __shared__ __align__(16) unsigned short XH[4][32][136];  // wave-private H slices
    __shared__ float p_g1w[128], p_g1b[128], p_b1[128];
    __shared__ float p_g2w[128], p_g2b[128], p_b2[128];
    __shared__ float p_w3[2][128];
    __shared__ float p_b3[2], p_ts[2];
    __shared__ unsigned int  msk[128];     // [b_loc*8+g]
    __shared__ unsigned char cvl[16];      // cvar|tflag byte per b_loc

    const int tid  = threadIdx.x;
    const int w    = tid >> 6, lane = tid & 63;
    const int lo   = lane & 15, hi = lane >> 4;
    const int l    = blockIdx.x & 31;
    const int grp  = blockIdx.x >> 5;

    // ---- stage per-latent params + per-block decisions (ONLY barrier) ----
    if (tid < 128) {
        int c = tid;
        p_g1w[c] = g1w[l * 128 + c];  p_g1b[c] = g1b[l * 128 + c];
        p_b1[c]  = pb1[l * 128 + c];  p_w3[0][c] = W3[l * 256 + c];
        msk[c]   = wsmask[l * 8192 + grp * 128 + c];
    } else {
        int c = tid - 128;
        p_g2w[c] = g2w[l * 128 + c];  p_g2b[c] = g2b[l * 128 + c];
        p_b2[c]  = pb2[l * 128 + c];  p_w3[1][c] = W3[l * 256 + 128 + c];
    }
    if (tid < 16) cvl[tid] = cvarpk[(size_t)(grp * 16 + tid) * 32 + l];
    if (tid == 0) {
        p_b3[0] = pb3[l * 2];  p_b3[1] = pb3[l * 2 + 1];
        p_ts[0] = tsc[l * 2];  p_ts[1] = tsc[l * 2 + 1];
    }
    __syncthreads();  // B0 — the only barrier

    // ================= build X B-frags in registers =================
    bf16x8 bq[2][4];
    #pragma unroll
    for (int nt = 0; nt < 2; ++nt) {
        int r  = w * 32 + nt * 16 + lo;
        int bl = r >> 3;
        int bg = grp * 16 + bl;
        unsigned int m32 = msk[r];
        unsigned int mq  = (m32 >> (hi * 8)) & 0xffu;
        const float4* zp = (const float4*)(z_sample + bg * 32 + hi * 8);
        float4 za = zp[0], zb = zp[1];
        uint4 f0;   // masked z (cols hi*8..+7)
        f0.x = pk2((mq & 1u)   ? za.x : 0.f, (mq & 2u)   ? za.y : 0.f);
        f0.y = pk2((mq & 4u)   ? za.z : 0.f, (mq & 8u)   ? za.w : 0.f);
        f0.z = pk2((mq & 16u)  ? zb.x : 0.f, (mq & 32u)  ? zb.y : 0.f);
        f0.w = pk2((mq & 64u)  ? zb.z : 0.f, (mq & 128u) ? zb.w : 0.f);
        uint4 f1;   // mask indicator as bf16 1.0
        f1.x = ((mq & 1u)   ? 0x3F80u : 0u) | ((mq & 2u)   ? 0x3F800000u : 0u);
        f1.y = ((mq & 4u)   ? 0x3F80u : 0u) | ((mq & 8u)   ? 0x3F800000u : 0u);
        f1.z = ((mq & 16u)  ? 0x3F80u : 0u) | ((mq & 32u)  ? 0x3F800000u : 0u);
        f1.w = ((mq & 64u)  ? 0x3F80u : 0u) | ((mq & 128u) ? 0x3F800000u : 0u);
        // frag2/frag3: [t one-hot (8) | z_shared (32) | pad (24)]
        unsigned int cb8 = cvl[bl];
        int lam = cb8 & 7, tf = (cb8 >> 3) & 1;
        int zsb = (hi == 0) ? 24 : (hi - 1) * 8;
        const float4* sp = (const float4*)(z_shared + bg * 32 + zsb);
        float4 sa = sp[0], sb = sp[1];
        uint4 fz;
        fz.x = pk2(sa.x, sa.y); fz.y = pk2(sa.z, sa.w);
        fz.z = pk2(sb.x, sb.y); fz.w = pk2(sb.z, sb.w);
        unsigned int ohw = tf ? (0x3F80u << ((lam & 1) << 4)) : 0u;
        int lq = lam >> 1;
        uint4 fo;
        fo.x = (lq == 0) ? ohw : 0u;
        fo.y = (lq == 1) ? ohw : 0u;
        fo.z = (lq == 2) ? ohw : 0u;
        fo.w = (lq == 3) ? ohw : 0u;
        bool h0 = (hi == 0);
        uint4 f2, f3;
        f2.x = h0 ? fo.x : fz.x;  f2.y = h0 ? fo.y : fz.y;
        f2.z = h0 ? fo.z : fz.z;  f2.w = h0 ? fo.w : fz.w;
        f3.x = h0 ? fz.x : 0u;    f3.y = h0 ? fz.y : 0u;
        f3.z = h0 ? fz.z : 0u;    f3.w = h0 ? fz.w : 0u;
        bq[nt][0] = u2f(f0); bq[nt][1] = u2f(f1);
        bq[nt][2] = u2f(f2); bq[nt][3] = u2f(f3);
    }

    const float inv128 = 1.0f / 128.0f;

    // ================= GEMM1: D[c][row] = W1 * X^T =================
    f32x4 acc[8][2];
    #pragma unroll
    for (int cb = 0; cb < 8; ++cb)
        #pragma unroll
        for (int nt = 0; nt < 2; ++nt) acc[cb][nt] = (f32x4){0.f, 0.f, 0.f, 0.f};
    {
        const unsigned short* w1p = wscr + (size_t)(l * 32) * 512 + lane * 8;
        #pragma unroll
        for (int ks = 0; ks < 4; ++ks) {
            #pragma unroll
            for (int half = 0; half < 2; ++half) {
                bf16x8 wf[4];
                #pragma unroll
                for (int q = 0; q < 4; ++q)
                    wf[q] = ld_frag(w1p + ((half * 4 + q) * 4 + ks) * 512);
                #pragma unroll
                for (int q = 0; q < 4; ++q) {
                    int cb = half * 4 + q;
                    acc[cb][0] = __builtin_amdgcn_mfma_f32_16x16x32_bf16(
                        wf[q], bq[0][ks], acc[cb][0], 0, 0, 0);
                    acc[cb][1] = __builtin_amdgcn_mfma_f32_16x16x32_bf16(
                        wf[q], bq[1][ks], acc[cb][1], 0, 0, 0);
                }
            }
        }
    }

    // ---- GN1: stats fully in-wave ----
    float s1[2] = {0.f, 0.f}, s2[2] = {0.f, 0.f};
    #pragma unroll
    for (int cb = 0; cb < 8; ++cb) {
        float4 b4 = *(const float4*)&p_b1[cb * 16 + hi * 4];
        #pragma unroll
        for (int rg = 0; rg < 4; ++rg) {
            float bias = ((const float*)&b4)[rg];
            #pragma unroll
            for (int nt = 0; nt < 2; ++nt) {
                float v = acc[cb][nt][rg] + bias;
                acc[cb][nt][rg] = v;
                s1[nt] += v;  s2[nt] += v * v;
            }
        }
    }
    float mu[2], rstd[2];
    #pragma unroll
    for (int nt = 0; nt < 2; ++nt) {
        s1[nt] += __shfl_xor(s1[nt], 16, 64);  s1[nt] += __shfl_xor(s1[nt], 32, 64);
        s2[nt] += __shfl_xor(s2[nt], 16, 64);  s2[nt] += __shfl_xor(s2[nt], 32, 64);
        float m_  = s1[nt] * inv128;
        float var = s2[nt] * inv128 - m_ * m_;
        mu[nt] = m_;  rstd[nt] = rsqrtf(var + 1e-5f);
    }
    // ---- normalize + SiLU -> wave-private H slice ----
    #pragma unroll
    for (int cb = 0; cb < 8; ++cb) {
        float4 gw4 = *(const float4*)&p_g1w[cb * 16 + hi * 4];
        float4 gb4 = *(const float4*)&p_g1b[cb * 16 + hi * 4];
        #pragma unroll
        for (int nt = 0; nt < 2; ++nt) {
            float sl[4];
            #pragma unroll
            for (int rg = 0; rg < 4; ++rg) {
                float x = (acc[cb][nt][rg] - mu[nt]) * rstd[nt] * ((const float*)&gw4)[rg]
                          + ((const float*)&gb4)[rg];
                sl[rg] = siluf(x);
            }
            *(uint2*)&XH[w][nt * 16 + lo][cb * 16 + hi * 4] =
                make_uint2(pk2(sl[0], sl[1]), pk2(sl[2], sl[3]));
        }
    }
    // (in-wave LDS RAW: compiler orders via lgkmcnt — no barrier needed)

    // ================= GEMM2: D[c][row] = W2 * H^T =================
    #pragma unroll
    for (int cb = 0; cb < 8; ++cb)
        #pragma unroll
        for (int nt = 0; nt < 2; ++nt) acc[cb][nt] = (f32x4){0.f, 0.f, 0.f, 0.f};
    {
        const unsigned short* w2p = wscr + (size_t)((32 + l) * 32) * 512 + lane * 8;
        #pragma unroll
        for (int ks = 0; ks < 4; ++ks) {
            bf16x8 bf0 = ld_frag(&XH[w][lo][ks * 32 + hi * 8]);
            bf16x8 bf1 = ld_frag(&XH[w][16 + lo][ks * 32 + hi * 8]);
            #pragma unroll
            for (int half = 0; half < 2; ++half) {
                bf16x8 wf[4];
                #pragma unroll
                for (int q = 0; q < 4; ++q)
                    wf[q] = ld_frag(w2p + ((half * 4 + q) * 4 + ks) * 512);
                #pragma unroll
                for (int q = 0; q < 4; ++q) {
                    int cb = half * 4 + q;
                    acc[cb][0] = __builtin_amdgcn_mfma_f32_16x16x32_bf16(
                        wf[q], bf0, acc[cb][0], 0, 0, 0);
                    acc[cb][1] = __builtin_amdgcn_mfma_f32_16x16x32_bf16(
                        wf[q], bf1, acc[cb][1], 0, 0, 0);
                }
            }
        }
    }

    // ---- GN2 stats in-wave ----
    float t1[2] = {0.f, 0.f}, t2[2] = {0.f, 0.f};
    #pragma unroll
    for (int cb = 0; cb < 8; ++cb) {
        float4 b4 = *(const float4*)&p_b2[cb * 16 + hi * 4];
        #pragma unroll
        for (int rg = 0; rg < 4; ++rg) {
            float bias = ((const float*)&b4)[rg];
            #pragma unroll
            for (int nt = 0; nt < 2; ++nt) {
                float v = acc[cb][nt][rg] + bias;
                acc[cb][nt][rg] = v;
                t1[nt] += v;  t2[nt] += v * v;
            }
        }
    }
    float mu2[2], rstd2[2];
    #pragma unroll
    for (int nt = 0; nt < 2; ++nt) {
        t1[nt] += __shfl_xor(t1[nt], 16, 64);  t1[nt] += __shfl_xor(t1[nt], 32, 64);
        t2[nt] += __shfl_xor(t2[nt], 16, 64);  t2[nt] += __shfl_xor(t2[nt], 32, 64);
        float m_  = t1[nt] * inv128;
        float var = t2[nt] * inv128 - m_ * m_;
        mu2[nt] = m_;  rstd2[nt] = rsqrtf(var + 1e-5f);
    }
    // ---- normalize + SiLU + 128->2 dot, in-wave ----
    float pmp[2] = {0.f, 0.f}, plp[2] = {0.f, 0.f};
    #pragma unroll
    for (int cb = 0; cb < 8; ++cb) {
        float4 gw4 = *(const float4*)&p_g2w[cb * 16 + hi * 4];
        float4 gb4 = *(const float4*)&p_g2b[cb * 16 + hi * 4];
        float4 w04 = *(const float4*)&p_w3[0][cb * 16 + hi * 4];
        float4 w14 = *(const float4*)&p_w3[1][cb * 16 + hi * 4];
        #pragma unroll
        for (int rg = 0; rg < 4; ++rg) {
            float wg = ((const float*)&gw4)[rg], gb = ((const float*)&gb4)[rg];
            float w0 = ((const float*)&w04)[rg], w1 = ((const float*)&w14)[rg];
            #pragma unroll
            for (int nt = 0; nt < 2; ++nt) {
                float x  = (acc[cb][nt][rg] - mu2[nt]) * rstd2[nt] * wg + gb;
                float sl = siluf(x);
                pmp[nt] += sl * w0;
                plp[nt] += sl * w1;
            }
        }
    }
    #pragma unroll
    for (int nt = 0; nt < 2; ++nt) {
        pmp[nt] += __shfl_xor(pmp[nt], 16, 64);  pmp[nt] += __shfl_xor(pmp[nt], 32, 64);
        plp[nt] += __shfl_xor(plp[nt], 16, 64);  plp[nt] += __shfl_xor(plp[nt], 32, 64);
    }

    // ---- tanh-scale + KLD + mean over g + accumulate ----
    {
        float sc0 = __expf(p_ts[0]), sc1 = __expf(p_ts[1]);
        float is0 = __expf(-p_ts[0]), is1 = __expf(-p_ts[1]);
        #pragma unroll
        for (int nt = 0; nt < 2; ++nt) {
            float pm = pmp[nt] + p_b3[0];
            float pl = plp[nt] + p_b3[1];
            float e0 = __expf(2.0f * pm * is0);
            pm = (1.0f - 2.0f * __fdividef(1.0f, e0 + 1.0f)) * sc0;
            float e1 = __expf(2.0f * pl * is1);
            pl = (1.0f - 2.0f * __fdividef(1.0f, e1 + 1.0f)) * sc1;
            int r  = w * 32 + nt * 16 + lo;
            int bg = grp * 16 + (r >> 3);
            float zm = z_mean[bg * 32 + l];
            float zl = z_logstd[bg * 32 + l];
            float vq = __expf(2.0f * zl);
            float d  = zm - pm;
            float kld = pl - zl + (vq + d * d) * 0.5f * __expf(-2.0f * pl) - 0.5f;
            kld += __shfl_xor(kld, 1, 64);
            kld += __shfl_xor(kld, 2, 64);
            kld += __shfl_xor(kld, 4, 64);
            if (hi == 0 && (lo & 7) == 0) atomicAdd(&out[bg], kld * 0.125f);
        }
    }
}

extern "C" void kernel_launch(void* const* d_in, const int* in_sizes, int n_in,
                              void* d_out, int out_size, void* d_ws, size_t ws_size,
                              hipStream_t stream) {
    const float* z_sample      = (const float*)d_in[0];
    const int*   target        = (const int*)d_in[1];
    const float* z_mean        = (const float*)d_in[2];
    const float* z_logstd      = (const float*)d_in[3];
    const float* z_shared      = (const float*)d_in[4];
    const float* u_gumbel      = (const float*)d_in[5];
    const float* u_adj         = (const float*)d_in[6];
    const float* target_params = (const float*)d_in[7];
    const float* enco_theta    = (const float*)d_in[8];
    const float* enco_gamma    = (const float*)d_in[9];
    const float* W1            = (const float*)d_in[10];
    const float* pb1           = (const float*)d_in[11];
    const float* g1w           = (const float*)d_in[12];
    const float* g1b           = (const float*)d_in[13];
    const float* W2            = (const float*)d_in[14];
    const float* pb2           = (const float*)d_in[15];
    const float* g2w           = (const float*)d_in[16];
    const float* g2b           = (const float*)d_in[17];
    const float* W3            = (const float*)d_in[18];
    const float* pb3           = (const float*)d_in[19];
    const float* tsc           = (const float*)d_in[20];

    unsigned char* cvarpk = (unsigned char*)d_ws;                          // 32 KB
    unsigned int*  wsmask = (unsigned int*)((char*)d_ws + 32768);          // 1 MB
    unsigned short* wscr  = (unsigned short*)((char*)d_ws + 32768 + 1048576); // 2 MB

    prep_kernel<<<1536, 256, 0, stream>>>(u_gumbel, u_adj, target_params,
                                          enco_theta, enco_gamma, target,
                                          W1, W2, (float*)d_out,
                                          cvarpk, wsmask, wscr);
    fused_kernel<<<2048, 256, 0, stream>>>(z_sample, z_mean, z_logstd, z_shared,
                                           pb1, g1w, g1b, pb2, g2w, g2b,
                                           W3, pb3, tsc, wscr, cvarpk, wsmask,
                                           (float*)d_out);
}

// Round 9
// 167.889 us; speedup vs baseline: 1.3074x; 1.0116x over previous
//
#include <hip/hip_runtime.h>
#include <hip/hip_bf16.h>

// Problem constants
#define B_DIM 1024
#define L_DIM 32
#define K_DIM 8
#define G_DIM 8
#define C_DIM 128
#define S_DIM 32
#define DIN   104   // 2L + K + S

typedef __bf16  bf16x8 __attribute__((ext_vector_type(8)));
typedef float   f32x4  __attribute__((ext_vector_type(4)));

union frag_u { uint4 u; bf16x8 v; };

static __device__ __forceinline__ unsigned int pk2(float a, float b) {
    __hip_bfloat162 h = __float22bfloat162_rn(make_float2(a, b));  // v_cvt_pk_bf16_f32
    union { __hip_bfloat162 h; unsigned int u; } v; v.h = h; return v.u;
}
static __device__ __forceinline__ bf16x8 ld_frag(const unsigned short* p) {
    frag_u t; t.u = *(const uint4*)p; return t.v;
}
static __device__ __forceinline__ bf16x8 u2f(uint4 u) {
    frag_u t; t.u = u; return t.v;
}
static __device__ __forceinline__ float siluf(float x) {
    return __fdividef(x, 1.0f + __expf(-x));
}

// ---------------------------------------------------------------------------
// Kernel 1 (merged): blocks [0,1024): per-b decisions -> cvarpk byte +
//   parent-mask bits wsmask[l][b][g]; zero d_out[b]. Gumbel argmax fp32 fast
//   path with fp64 fallback on near-ties (prob ~1e-4). Adjacency stays fp64.
//   blocks [1024,1536): W1/W2 fp32->bf16 fragment repack.
// (Measured R2-R8: total-fused gap constant ~92us across prep variants ->
//  prep is NOT the limiter; kept as-is.)
// ---------------------------------------------------------------------------
__global__ __launch_bounds__(256) void prep_kernel(
    const float* __restrict__ u_gumbel,      // [B,L,K]
    const float* __restrict__ u_adj,         // [B,G,K,K]
    const float* __restrict__ target_params, // [L,K]
    const float* __restrict__ enco_theta,    // [K,K]
    const float* __restrict__ enco_gamma,    // [K,K]
    const int*   __restrict__ target,        // [B]
    const float* __restrict__ W1,            // [32][128][104]
    const float* __restrict__ W2,            // [32][128][128]
    float*       __restrict__ out,           // [B] (zeroed here, atomics later)
    unsigned char* __restrict__ cvarpk,      // [B][32]  cvar | tflag<<3
    unsigned int*  __restrict__ wsmask,      // [L][B][G] parent-mask bits over j
    unsigned short* __restrict__ wscr)       // bf16 frag-ordered weights
{
    const int t = threadIdx.x;
    if (blockIdx.x >= 1024) {
        // ---- weight repack: frag F = (which*32+l)*32 + cb*4 + ks ----
        int gtid  = (blockIdx.x - 1024) * 256 + t;   // [0, 131072)
        int lane  = gtid & 63;
        int ks    = (gtid >> 6) & 3;
        int mt    = (gtid >> 8) & 3;
        int wm    = (gtid >> 10) & 1;
        int l     = (gtid >> 11) & 31;
        int which = gtid >> 16;
        int m  = 16 * (4 * wm + mt) + (lane & 15);
        int k0 = ks * 32 + (lane >> 4) * 8;
        uint4 o;
        if (which == 0) {
            if (k0 >= 104) {
                o = make_uint4(0u, 0u, 0u, 0u);
            } else {
                const float* p = W1 + (size_t)l * 13312 + m * 104 + k0;
                float4 a = *(const float4*)p, bq = *(const float4*)(p + 4);
                o = make_uint4(pk2(a.x, a.y), pk2(a.z, a.w), pk2(bq.x, bq.y), pk2(bq.z, bq.w));
            }
        } else {
            const float* p = W2 + (size_t)l * 16384 + m * 128 + k0;
            float4 a = *(const float4*)p, bq = *(const float4*)(p + 4);
            o = make_uint4(pk2(a.x, a.y), pk2(a.z, a.w), pk2(bq.x, bq.y), pk2(bq.z, bq.w));
        }
        *(uint4*)(wscr + (size_t)gtid * 8) = o;
        return;
    }

    __shared__ double ep[64];
    __shared__ unsigned char cv8[32];
    __shared__ unsigned long long adjb[8];
    const int b = blockIdx.x;
    if (t < 64) {
        double th = (double)enco_theta[t];
        double ga = (double)enco_gamma[t];
        ep[t] = (1.0 / (1.0 + exp(-th))) * (1.0 / (1.0 + exp(-ga)));
    }
    if (t == 0) out[b] = 0.0f;
    __syncthreads();

    // gumbel argmax: thread t = l*8 + k; fp32 fast path, fp64 fallback
    {
        const int l = t >> 3, k = t & 7;
        float uf = u_gumbel[b * 256 + t];
        float gf = -__logf(-__logf(uf + 1e-10f) + 1e-10f);
        float vf = target_params[t] + gf;
        float vm = vf; int bk = k;
        #pragma unroll
        for (int off = 1; off < 8; off <<= 1) {
            float ov = __shfl_xor(vm, off, 64);
            int  obk = __shfl_xor(bk, off, 64);
            if (ov > vm || (ov == vm && obk < bk)) { vm = ov; bk = obk; }
        }
        int amb = ((k != bk) && (vm - vf < 1e-3f)) ? 1 : 0;
        #pragma unroll
        for (int off = 1; off < 8; off <<= 1) amb |= __shfl_xor(amb, off, 64);
        if (amb) {   // group-uniform; rare
            double ud = (double)uf;
            double gd = -log(-log(ud + 1e-10) + 1e-10);
            double vd = (double)target_params[t] + gd;
            int bk2 = k;
            #pragma unroll
            for (int off = 1; off < 8; off <<= 1) {
                double ov = __shfl_xor(vd, off, 64);
                int   obk = __shfl_xor(bk2, off, 64);
                if (ov > vd || (ov == vd && obk < bk2)) { vd = ov; bk2 = obk; }
            }
            bk = bk2;
        }
        if (k == 0) {
            int tg = target[b];
            unsigned char pkd = (unsigned char)(bk | ((bk == tg) ? 8 : 0));
            cvarpk[b * 32 + l] = pkd;
            cv8[l] = pkd;
        }
    }
    // adjacency: wave w handles g = w and g = w+4; bits into LDS only
    {
        const int wv = t >> 6, lane = t & 63;
        #pragma unroll
        for (int q = 0; q < 2; ++q) {
            int gg = wv + 4 * q;
            double u = (double)u_adj[b * 512 + gg * 64 + lane];
            unsigned long long m = __ballot(u < ep[lane]);
            if (lane == 0) adjb[gg] = m;
        }
    }
    __syncthreads();

    // parent-mask: thread (g = t>>5, l = t&31): bit j = adj[g][cvar_j][cvar_l], j!=l
    {
        const int g = t >> 5, l = t & 31;
        int lam = cv8[l] & 7;
        unsigned long long bits = adjb[g] >> lam;   // bit (kap*8) now selects
        unsigned int mask = 0u;
        #pragma unroll
        for (int j = 0; j < 32; ++j) {
            int kap = cv8[j] & 7;
            mask |= ((unsigned int)(bits >> (kap * 8)) & 1u) << j;
        }
        mask &= ~(1u << l);
        wsmask[l * 8192 + b * 8 + g] = mask;
    }
}

// ---------------------------------------------------------------------------
// Kernel 2: wave-autonomous fused pipeline with SOFTWARE-PIPELINED weight
// streaming. Grid 2048: blockIdx = grp*32 + l. Block = 4 waves x 32 rows.
// GEMM loops keep a 4-frag load batch in flight under the current batch's
// MFMAs; GEMM2's first batch prefetched during the GN1/SiLU epilogue.
// ---------------------------------------------------------------------------
__global__ __launch_bounds__(256, 3) void fused_kernel(
    const float* __restrict__ z_sample,   // [B,32]
    const float* __restrict__ z_mean,     // [B,32]
    const float* __restrict__ z_logstd,   // [B,32]
    const float* __restrict__ z_shared,   // [B,32]
    const float* __restrict__ pb1,        // [32][128]
    const float* __restrict__ g1w,
    const float* __restrict__ g1b,
    const float* __restrict__ pb2,
    const float* __restrict__ g2w,
    const float* __restrict__ g2b,
    const float* __restrict__ W3,         // [32][2][128]
    const float* __restrict__ pb3,        // [32][2]
    const float* __restrict__ tsc,        // [32][2]
    const unsigned short* __restrict__ wscr,    // bf16 frag-ordered weights
    const unsigned char*  __restrict__ cvarpk,  // [B][32]
    const unsigned int*   __restrict__ wsmask,  // [L][B][G]
    float* __restrict__ out)                    // [B]
{
    __shared__ __align__(16) unsigned short XH[4][32][136];  // wave-private H slices
    __shared__ float p_g1w[128], p_g1b[128], p_b1[128];
    __shared__ float p_g2w[128], p_g2b[128], p_b2[128];
    __shared__ float p_w3[2][128];
    __shared__ float p_b3[2], p_ts[2];
    __shared__ unsigned int  msk[128];     // [b_loc*8+g]
    __shared__ unsigned char cvl[16];      // cvar|tflag byte per b_loc

    const int tid  = threadIdx.x;
    const int w    = tid >> 6, lane = tid & 63;
    const int lo   = lane & 15, hi = lane >> 4;
    const int l    = blockIdx.x & 31;
    const int grp  = blockIdx.x >> 5;

    // ---- stage per-latent params + per-block decisions (ONLY barrier) ----
    if (tid < 128) {
        int c = tid;
        p_g1w[c] = g1w[l * 128 + c];  p_g1b[c] = g1b[l * 128 + c];
        p_b1[c]  = pb1[l * 128 + c];  p_w3[0][c] = W3[l * 256 + c];
        msk[c]   = wsmask[l * 8192 + grp * 128 + c];
    } else {
        int c = tid - 128;
        p_g2w[c] = g2w[l * 128 + c];  p_g2b[c] = g2b[l * 128 + c];
        p_b2[c]  = pb2[l * 128 + c];  p_w3[1][c] = W3[l * 256 + 128 + c];
    }
    if (tid < 16) cvl[tid] = cvarpk[(size_t)(grp * 16 + tid) * 32 + l];
    if (tid == 0) {
        p_b3[0] = pb3[l * 2];  p_b3[1] = pb3[l * 2 + 1];
        p_ts[0] = tsc[l * 2];  p_ts[1] = tsc[l * 2 + 1];
    }
    __syncthreads();  // B0 — the only barrier

    // ================= build X B-frags in registers (+early KLD operands) ====
    bf16x8 bq[2][4];
    float zmv[2], zlv[2];
    #pragma unroll
    for (int nt = 0; nt < 2; ++nt) {
        int r  = w * 32 + nt * 16 + lo;
        int bl = r >> 3;
        int bg = grp * 16 + bl;
        zmv[nt] = z_mean[bg * 32 + l];       // early: consumed at tail
        zlv[nt] = z_logstd[bg * 32 + l];
        unsigned int m32 = msk[r];
        unsigned int mq  = (m32 >> (hi * 8)) & 0xffu;
        const float4* zp = (const float4*)(z_sample + bg * 32 + hi * 8);
        float4 za = zp[0], zb = zp[1];
        uint4 f0;   // masked z (cols hi*8..+7)
        f0.x = pk2((mq & 1u)   ? za.x : 0.f, (mq & 2u)   ? za.y : 0.f);
        f0.y = pk2((mq & 4u)   ? za.z : 0.f, (mq & 8u)   ? za.w : 0.f);
        f0.z = pk2((mq & 16u)  ? zb.x : 0.f, (mq & 32u)  ? zb.y : 0.f);
        f0.w = pk2((mq & 64u)  ? zb.z : 0.f, (mq & 128u) ? zb.w : 0.f);
        uint4 f1;   // mask indicator as bf16 1.0
        f1.x = ((mq & 1u)   ? 0x3F80u : 0u) | ((mq & 2u)   ? 0x3F800000u : 0u);
        f1.y = ((mq & 4u)   ? 0x3F80u : 0u) | ((mq & 8u)   ? 0x3F800000u : 0u);
        f1.z = ((mq & 16u)  ? 0x3F80u : 0u) | ((mq & 32u)  ? 0x3F800000u : 0u);
        f1.w = ((mq & 64u)  ? 0x3F80u : 0u) | ((mq & 128u) ? 0x3F800000u : 0u);
        // frag2/frag3: [t one-hot (8) | z_shared (32) | pad (24)]
        unsigned int cb8 = cvl[bl];
        int lam = cb8 & 7, tf = (cb8 >> 3) & 1;
        int zsb = (hi == 0) ? 24 : (hi - 1) * 8;
        const float4* sp = (const float4*)(z_shared + bg * 32 + zsb);
        float4 sa = sp[0], sb = sp[1];
        uint4 fz;
        fz.x = pk2(sa.x, sa.y); fz.y = pk2(sa.z, sa.w);
        fz.z = pk2(sb.x, sb.y); fz.w = pk2(sb.z, sb.w);
        unsigned int ohw = tf ? (0x3F80u << ((lam & 1) << 4)) : 0u;
        int lq = lam >> 1;
        uint4 fo;
        fo.x = (lq == 0) ? ohw : 0u;
        fo.y = (lq == 1) ? ohw : 0u;
        fo.z = (lq == 2) ? ohw : 0u;
        fo.w = (lq == 3) ? ohw : 0u;
        bool h0 = (hi == 0);
        uint4 f2, f3;
        f2.x = h0 ? fo.x : fz.x;  f2.y = h0 ? fo.y : fz.y;
        f2.z = h0 ? fo.z : fz.z;  f2.w = h0 ? fo.w : fz.w;
        f3.x = h0 ? fz.x : 0u;    f3.y = h0 ? fz.y : 0u;
        f3.z = h0 ? fz.z : 0u;    f3.w = h0 ? fz.w : 0u;
        bq[nt][0] = u2f(f0); bq[nt][1] = u2f(f1);
        bq[nt][2] = u2f(f2); bq[nt][3] = u2f(f3);
    }

    const float inv128 = 1.0f / 128.0f;

    // ================= GEMM1 (software-pipelined W1 stream) =================
    f32x4 acc[8][2];
    #pragma unroll
    for (int cb = 0; cb < 8; ++cb)
        #pragma unroll
        for (int nt = 0; nt < 2; ++nt) acc[cb][nt] = (f32x4){0.f, 0.f, 0.f, 0.f};
    {
        const unsigned short* w1p = wscr + (size_t)(l * 32) * 512 + lane * 8;
        bf16x8 wfa[4], wfb[4], wfn[4];
        #pragma unroll
        for (int q = 0; q < 4; ++q) wfa[q] = ld_frag(w1p + (q * 4 + 0) * 512);
        #pragma unroll
        for (int ks = 0; ks < 4; ++ks) {
            #pragma unroll
            for (int q = 0; q < 4; ++q)
                wfb[q] = ld_frag(w1p + ((4 + q) * 4 + ks) * 512);     // half1, in flight
            #pragma unroll
            for (int q = 0; q < 4; ++q) {
                acc[q][0] = __builtin_amdgcn_mfma_f32_16x16x32_bf16(
                    wfa[q], bq[0][ks], acc[q][0], 0, 0, 0);
                acc[q][1] = __builtin_amdgcn_mfma_f32_16x16x32_bf16(
                    wfa[q], bq[1][ks], acc[q][1], 0, 0, 0);
            }
            if (ks < 3) {
                #pragma unroll
                for (int q = 0; q < 4; ++q)
                    wfn[q] = ld_frag(w1p + (q * 4 + ks + 1) * 512);   // half0 next ks
            }
            #pragma unroll
            for (int q = 0; q < 4; ++q) {
                acc[4 + q][0] = __builtin_amdgcn_mfma_f32_16x16x32_bf16(
                    wfb[q], bq[0][ks], acc[4 + q][0], 0, 0, 0);
                acc[4 + q][1] = __builtin_amdgcn_mfma_f32_16x16x32_bf16(
                    wfb[q], bq[1][ks], acc[4 + q][1], 0, 0, 0);
            }
            if (ks < 3) {
                #pragma unroll
                for (int q = 0; q < 4; ++q) wfa[q] = wfn[q];
            }
        }
    }

    // ---- GN1: stats fully in-wave ----
    float s1[2] = {0.f, 0.f}, s2[2] = {0.f, 0.f};
    #pragma unroll
    for (int cb = 0; cb < 8; ++cb) {
        float4 b4 = *(const float4*)&p_b1[cb * 16 + hi * 4];
        #pragma unroll
        for (int rg = 0; rg < 4; ++rg) {
            float bias = ((const float*)&b4)[rg];
            #pragma unroll
            for (int nt = 0; nt < 2; ++nt) {
                float v = acc[cb][nt][rg] + bias;
                acc[cb][nt][rg] = v;
                s1[nt] += v;  s2[nt] += v * v;
            }
        }
    }
    const unsigned short* w2p = wscr + (size_t)((32 + l) * 32) * 512 + lane * 8;
    bf16x8 w2a[4];
    #pragma unroll
    for (int q = 0; q < 4; ++q) w2a[q] = ld_frag(w2p + (q * 4 + 0) * 512);  // GEMM2 prefetch
    float mu[2], rstd[2];
    #pragma unroll
    for (int nt = 0; nt < 2; ++nt) {
        s1[nt] += __shfl_xor(s1[nt], 16, 64);  s1[nt] += __shfl_xor(s1[nt], 32, 64);
        s2[nt] += __shfl_xor(s2[nt], 16, 64);  s2[nt] += __shfl_xor(s2[nt], 32, 64);
        float m_  = s1[nt] * inv128;
        float var = s2[nt] * inv128 - m_ * m_;
        mu[nt] = m_;  rstd[nt] = rsqrtf(var + 1e-5f);
    }
    // ---- normalize + SiLU -> wave-private H slice ----
    #pragma unroll
    for (int cb = 0; cb < 8; ++cb) {
        float4 gw4 = *(const float4*)&p_g1w[cb * 16 + hi * 4];
        float4 gb4 = *(const float4*)&p_g1b[cb * 16 + hi * 4];
        #pragma unroll
        for (int nt = 0; nt < 2; ++nt) {
            float sl[4];
            #pragma unroll
            for (int rg = 0; rg < 4; ++rg) {
                float x = (acc[cb][nt][rg] - mu[nt]) * rstd[nt] * ((const float*)&gw4)[rg]
                          + ((const float*)&gb4)[rg];
                sl[rg] = siluf(x);
            }
            *(uint2*)&XH[w][nt * 16 + lo][cb * 16 + hi * 4] =
                make_uint2(pk2(sl[0], sl[1]), pk2(sl[2], sl[3]));
        }
    }
    // (in-wave LDS RAW: ordered by the per-wave LDS pipeline — no barrier)

    // ================= GEMM2 (software-pipelined W2 stream) =================
    #pragma unroll
    for (int cb = 0; cb < 8; ++cb)
        #pragma unroll
        for (int nt = 0; nt < 2; ++nt) acc[cb][nt] = (f32x4){0.f, 0.f, 0.f, 0.f};
    {
        bf16x8 wfb[4], wfn[4];
        #pragma unroll
        for (int ks = 0; ks < 4; ++ks) {
            bf16x8 bf0 = ld_frag(&XH[w][lo][ks * 32 + hi * 8]);
            bf16x8 bf1 = ld_frag(&XH[w][16 + lo][ks * 32 + hi * 8]);
            #pragma unroll
            for (int q = 0; q < 4; ++q)
                wfb[q] = ld_frag(w2p + ((4 + q) * 4 + ks) * 512);
            #pragma unroll
            for (int q = 0; q < 4; ++q) {
                acc[q][0] = __builtin_amdgcn_mfma_f32_16x16x32_bf16(
                    w2a[q], bf0, acc[q][0], 0, 0, 0);
                acc[q][1] = __builtin_amdgcn_mfma_f32_16x16x32_bf16(
                    w2a[q], bf1, acc[q][1], 0, 0, 0);
            }
            if (ks < 3) {
                #pragma unroll
                for (int q = 0; q < 4; ++q)
                    wfn[q] = ld_frag(w2p + (q * 4 + ks + 1) * 512);
            }
            #pragma unroll
            for (int q = 0; q < 4; ++q) {
                acc[4 + q][0] = __builtin_amdgcn_mfma_f32_16x16x32_bf16(
                    wfb[q], bf0, acc[4 + q][0], 0, 0, 0);
                acc[4 + q][1] = __builtin_amdgcn_mfma_f32_16x16x32_bf16(
                    wfb[q], bf1, acc[4 + q][1], 0, 0, 0);
            }
            if (ks < 3) {
                #pragma unroll
                for (int q = 0; q < 4; ++q) w2a[q] = wfn[q];
            }
        }
    }

    // ---- GN2 stats in-wave ----
    float t1[2] = {0.f, 0.f}, t2[2] = {0.f, 0.f};
    #pragma unroll
    for (int cb = 0; cb < 8; ++cb) {
        float4 b4 = *(const float4*)&p_b2[cb * 16 + hi * 4];
        #pragma unroll
        for (int rg = 0; rg < 4; ++rg) {
            float bias = ((const float*)&b4)[rg];
            #pragma unroll
            for (int nt = 0; nt < 2; ++nt) {
                float v = acc[cb][nt][rg] + bias;
                acc[cb][nt][rg] = v;
                t1[nt] += v;  t2[nt] += v * v;
            }
        }
    }
    float mu2[2], rstd2[2];
    #pragma unroll
    for (int nt = 0; nt < 2; ++nt) {
        t1[nt] += __shfl_xor(t1[nt], 16, 64);  t1[nt] += __shfl_xor(t1[nt], 32, 64);
        t2[nt] += __shfl_xor(t2[nt], 16, 64);  t2[nt] += __shfl_xor(t2[nt], 32, 64);
        float m_  = t1[nt] * inv128;
        float var = t2[nt] * inv128 - m_ * m_;
        mu2[nt] = m_;  rstd2[nt] = rsqrtf(var + 1e-5f);
    }
    // ---- normalize + SiLU + 128->2 dot, in-wave ----
    float pmp[2] = {0.f, 0.f}, plp[2] = {0.f, 0.f};
    #pragma unroll
    for (int cb = 0; cb < 8; ++cb) {
        float4 gw4 = *(const float4*)&p_g2w[cb * 16 + hi * 4];
        float4 gb4 = *(const float4*)&p_g2b[cb * 16 + hi * 4];
        float4 w04 = *(const float4*)&p_w3[0][cb * 16 + hi * 4];
        float4 w14 = *(const float4*)&p_w3[1][cb * 16 + hi * 4];
        #pragma unroll
        for (int rg = 0; rg < 4; ++rg) {
            float wg = ((const float*)&gw4)[rg], gb = ((const float*)&gb4)[rg];
            float w0 = ((const float*)&w04)[rg], w1 = ((const float*)&w14)[rg];
            #pragma unroll
            for (int nt = 0; nt < 2; ++nt) {
                float x  = (acc[cb][nt][rg] - mu2[nt]) * rstd2[nt] * wg + gb;
                float sl = siluf(x);
                pmp[nt] += sl * w0;
                plp[nt] += sl * w1;
            }
        }
    }
    #pragma unroll
    for (int nt = 0; nt < 2; ++nt) {
        pmp[nt] += __shfl_xor(pmp[nt], 16, 64);  pmp[nt] += __shfl_xor(pmp[nt], 32, 64);
        plp[nt] += __shfl_xor(plp[nt], 16, 64);  plp[nt] += __shfl_xor(plp[nt], 32, 64);
    }

    // ---- tanh-scale + KLD + mean over g + accumulate ----
    {
        float sc0 = __expf(p_ts[0]), sc1 = __expf(p_ts[1]);
        float is0 = __expf(-p_ts[0]), is1 = __expf(-p_ts[1]);
        #pragma unroll
        for (int nt = 0; nt < 2; ++nt) {
            float pm = pmp[nt] + p_b3[0];
            float pl = plp[nt] + p_b3[1];
            float e0 = __expf(2.0f * pm * is0);
            pm = (1.0f - 2.0f * __fdividef(1.0f, e0 + 1.0f)) * sc0;
            float e1 = __expf(2.0f * pl * is1);
            pl = (1.0f - 2.0f * __fdividef(1.0f, e1 + 1.0f)) * sc1;
            int r  = w * 32 + nt * 16 + lo;
            int bg = grp * 16 + (r >> 3);
            float vq = __expf(2.0f * zlv[nt]);
            float d  = zmv[nt] - pm;
            float kld = pl - zlv[nt] + (vq + d * d) * 0.5f * __expf(-2.0f * pl) - 0.5f;
            kld += __shfl_xor(kld, 1, 64);
            kld += __shfl_xor(kld, 2, 64);
            kld += __shfl_xor(kld, 4, 64);
            if (hi == 0 && (lo & 7) == 0) atomicAdd(&out[bg], kld * 0.125f);
        }
    }
}

extern "C" void kernel_launch(void* const* d_in, const int* in_sizes, int n_in,
                              void* d_out, int out_size, void* d_ws, size_t ws_size,
                              hipStream_t stream) {
    const float* z_sample      = (const float*)d_in[0];
    const int*   target        = (const int*)d_in[1];
    const float* z_mean        = (const float*)d_in[2];
    const float* z_logstd      = (const float*)d_in[3];
    const float* z_shared      = (const float*)d_in[4];
    const float* u_gumbel      = (const float*)d_in[5];
    const float* u_adj         = (const float*)d_in[6];
    const float* target_params = (const float*)d_in[7];
    const float* enco_theta    = (const float*)d_in[8];
    const float* enco_gamma    = (const float*)d_in[9];
    const float* W1            = (const float*)d_in[10];
    const float* pb1           = (const float*)d_in[11];
    const float* g1w           = (const float*)d_in[12];
    const float* g1b           = (const float*)d_in[13];
    const float* W2            = (const float*)d_in[14];
    const float* pb2           = (const float*)d_in[15];
    const float* g2w           = (const float*)d_in[16];
    const float* g2b           = (const float*)d_in[17];
    const float* W3            = (const float*)d_in[18];
    const float* pb3           = (const float*)d_in[19];
    const float* tsc           = (const float*)d_in[20];

    unsigned char* cvarpk = (unsigned char*)d_ws;                          // 32 KB
    unsigned int*  wsmask = (unsigned int*)((char*)d_ws + 32768);          // 1 MB
    unsigned short* wscr  = (unsigned short*)((char*)d_ws + 32768 + 1048576); // 2 MB

    prep_kernel<<<1536, 256, 0, stream>>>(u_gumbel, u_adj, target_params,
                                          enco_theta, enco_gamma, target,
                                          W1, W2, (float*)d_out,
                                          cvarpk, wsmask, wscr);
    fused_kernel<<<2048, 256, 0, stream>>>(z_sample, z_mean, z_logstd, z_shared,
                                           pb1, g1w, g1b, pb2, g2w, g2b,
                                           W3, pb3, tsc, wscr, cvarpk, wsmask,
                                           (float*)d_out);
}

// Round 10
// 167.543 us; speedup vs baseline: 1.3101x; 1.0021x over previous
//
#include <hip/hip_runtime.h>
#include <hip/hip_bf16.h>

// Problem constants
#define B_DIM 1024
#define L_DIM 32
#define K_DIM 8
#define G_DIM 8
#define C_DIM 128
#define S_DIM 32
#define DIN   104   // 2L + K + S

typedef __bf16  bf16x8 __attribute__((ext_vector_type(8)));
typedef float   f32x4  __attribute__((ext_vector_type(4)));

union frag_u { uint4 u; bf16x8 v; };

static __device__ __forceinline__ unsigned int pk2(float a, float b) {
    __hip_bfloat162 h = __float22bfloat162_rn(make_float2(a, b));  // v_cvt_pk_bf16_f32
    union { __hip_bfloat162 h; unsigned int u; } v; v.h = h; return v.u;
}
static __device__ __forceinline__ bf16x8 ld_frag(const unsigned short* p) {
    frag_u t; t.u = *(const uint4*)p; return t.v;
}
static __device__ __forceinline__ float siluf(float x) {
    return __fdividef(x, 1.0f + __expf(-x));
}

// ---------------------------------------------------------------------------
// Kernel 1 (merged): blocks [0,1024): per-b decisions -> cvarpk byte +
//   parent-mask bits wsmask[l][b][g]; zero d_out[b].
//   blocks [1024,1536): W1/W2 fp32->bf16 fragment repack.
// (R2-R8 measured: total-fused gap constant ~92us across prep variants ->
//  prep is not the limiter; unchanged.)
// ---------------------------------------------------------------------------
__global__ __launch_bounds__(256) void prep_kernel(
    const float* __restrict__ u_gumbel,      // [B,L,K]
    const float* __restrict__ u_adj,         // [B,G,K,K]
    const float* __restrict__ target_params, // [L,K]
    const float* __restrict__ enco_theta,    // [K,K]
    const float* __restrict__ enco_gamma,    // [K,K]
    const int*   __restrict__ target,        // [B]
    const float* __restrict__ W1,            // [32][128][104]
    const float* __restrict__ W2,            // [32][128][128]
    float*       __restrict__ out,           // [B]
    unsigned char* __restrict__ cvarpk,      // [B][32]  cvar | tflag<<3
    unsigned int*  __restrict__ wsmask,      // [L][B][G]
    unsigned short* __restrict__ wscr)       // bf16 frag-ordered weights
{
    const int t = threadIdx.x;
    if (blockIdx.x >= 1024) {
        int gtid  = (blockIdx.x - 1024) * 256 + t;   // [0, 131072)
        int lane  = gtid & 63;
        int ks    = (gtid >> 6) & 3;
        int mt    = (gtid >> 8) & 3;
        int wm    = (gtid >> 10) & 1;
        int l     = (gtid >> 11) & 31;
        int which = gtid >> 16;
        int m  = 16 * (4 * wm + mt) + (lane & 15);
        int k0 = ks * 32 + (lane >> 4) * 8;
        uint4 o;
        if (which == 0) {
            if (k0 >= 104) {
                o = make_uint4(0u, 0u, 0u, 0u);
            } else {
                const float* p = W1 + (size_t)l * 13312 + m * 104 + k0;
                float4 a = *(const float4*)p, bq = *(const float4*)(p + 4);
                o = make_uint4(pk2(a.x, a.y), pk2(a.z, a.w), pk2(bq.x, bq.y), pk2(bq.z, bq.w));
            }
        } else {
            const float* p = W2 + (size_t)l * 16384 + m * 128 + k0;
            float4 a = *(const float4*)p, bq = *(const float4*)(p + 4);
            o = make_uint4(pk2(a.x, a.y), pk2(a.z, a.w), pk2(bq.x, bq.y), pk2(bq.z, bq.w));
        }
        *(uint4*)(wscr + (size_t)gtid * 8) = o;
        return;
    }

    __shared__ double ep[64];
    __shared__ unsigned char cv8[32];
    __shared__ unsigned long long adjb[8];
    const int b = blockIdx.x;
    if (t < 64) {
        double th = (double)enco_theta[t];
        double ga = (double)enco_gamma[t];
        ep[t] = (1.0 / (1.0 + exp(-th))) * (1.0 / (1.0 + exp(-ga)));
    }
    if (t == 0) out[b] = 0.0f;
    __syncthreads();

    {
        const int l = t >> 3, k = t & 7;
        float uf = u_gumbel[b * 256 + t];
        float gf = -__logf(-__logf(uf + 1e-10f) + 1e-10f);
        float vf = target_params[t] + gf;
        float vm = vf; int bk = k;
        #pragma unroll
        for (int off = 1; off < 8; off <<= 1) {
            float ov = __shfl_xor(vm, off, 64);
            int  obk = __shfl_xor(bk, off, 64);
            if (ov > vm || (ov == vm && obk < bk)) { vm = ov; bk = obk; }
        }
        int amb = ((k != bk) && (vm - vf < 1e-3f)) ? 1 : 0;
        #pragma unroll
        for (int off = 1; off < 8; off <<= 1) amb |= __shfl_xor(amb, off, 64);
        if (amb) {
            double ud = (double)uf;
            double gd = -log(-log(ud + 1e-10) + 1e-10);
            double vd = (double)target_params[t] + gd;
            int bk2 = k;
            #pragma unroll
            for (int off = 1; off < 8; off <<= 1) {
                double ov = __shfl_xor(vd, off, 64);
                int   obk = __shfl_xor(bk2, off, 64);
                if (ov > vd || (ov == vd && obk < bk2)) { vd = ov; bk2 = obk; }
            }
            bk = bk2;
        }
        if (k == 0) {
            int tg = target[b];
            unsigned char pkd = (unsigned char)(bk | ((bk == tg) ? 8 : 0));
            cvarpk[b * 32 + l] = pkd;
            cv8[l] = pkd;
        }
    }
    {
        const int wv = t >> 6, lane = t & 63;
        #pragma unroll
        for (int q = 0; q < 2; ++q) {
            int gg = wv + 4 * q;
            double u = (double)u_adj[b * 512 + gg * 64 + lane];
            unsigned long long m = __ballot(u < ep[lane]);
            if (lane == 0) adjb[gg] = m;
        }
    }
    __syncthreads();

    {
        const int g = t >> 5, l = t & 31;
        int lam = cv8[l] & 7;
        unsigned long long bits = adjb[g] >> lam;
        unsigned int mask = 0u;
        #pragma unroll
        for (int j = 0; j < 32; ++j) {
            int kap = cv8[j] & 7;
            mask |= ((unsigned int)(bits >> (kap * 8)) & 1u) << j;
        }
        mask &= ~(1u << l);
        wsmask[l * 8192 + b * 8 + g] = mask;
    }
}

// ---------------------------------------------------------------------------
// Kernel 2: wave-autonomous fused pipeline, X staged via LDS (frees 32 VGPRs)
// to hit 4 waves/SIMD. Grid 2048: blockIdx = grp*32 + l. 4 waves x 32 rows.
// Weight frags streamed from L2 scratch in 2-frag lookahead batches.
// ---------------------------------------------------------------------------
__global__ __launch_bounds__(256, 4) void fused_kernel(
    const float* __restrict__ z_sample,   // [B,32]
    const float* __restrict__ z_mean,     // [B,32]
    const float* __restrict__ z_logstd,   // [B,32]
    const float* __restrict__ z_shared,   // [B,32]
    const float* __restrict__ pb1,        // [32][128]
    const float* __restrict__ g1w,
    const float* __restrict__ g1b,
    const float* __restrict__ pb2,
    const float* __restrict__ g2w,
    const float* __restrict__ g2b,
    const float* __restrict__ W3,         // [32][2][128]
    const float* __restrict__ pb3,        // [32][2]
    const float* __restrict__ tsc,        // [32][2]
    const unsigned short* __restrict__ wscr,    // bf16 frag-ordered weights
    const unsigned char*  __restrict__ cvarpk,  // [B][32]
    const unsigned int*   __restrict__ wsmask,  // [L][B][G]
    float* __restrict__ out)                    // [B]
{
    __shared__ __align__(16) unsigned short XH[4][32][136];  // wave-private X->H slices
    __shared__ float p_g1w[128], p_g1b[128], p_b1[128];
    __shared__ float p_g2w[128], p_g2b[128], p_b2[128];
    __shared__ float p_w3[2][128];
    __shared__ float p_b3[2], p_ts[2];
    __shared__ unsigned int  msk[128];
    __shared__ unsigned char cvl[16];

    const int tid  = threadIdx.x;
    const int w    = tid >> 6, lane = tid & 63;
    const int lo   = lane & 15, hi = lane >> 4;
    const int l    = blockIdx.x & 31;
    const int grp  = blockIdx.x >> 5;

    // ---- stage per-latent params + per-block decisions (ONLY barrier) ----
    if (tid < 128) {
        int c = tid;
        p_g1w[c] = g1w[l * 128 + c];  p_g1b[c] = g1b[l * 128 + c];
        p_b1[c]  = pb1[l * 128 + c];  p_w3[0][c] = W3[l * 256 + c];
        msk[c]   = wsmask[l * 8192 + grp * 128 + c];
    } else {
        int c = tid - 128;
        p_g2w[c] = g2w[l * 128 + c];  p_g2b[c] = g2b[l * 128 + c];
        p_b2[c]  = pb2[l * 128 + c];  p_w3[1][c] = W3[l * 256 + 128 + c];
    }
    if (tid < 16) cvl[tid] = cvarpk[(size_t)(grp * 16 + tid) * 32 + l];
    if (tid == 0) {
        p_b3[0] = pb3[l * 2];  p_b3[1] = pb3[l * 2 + 1];
        p_ts[0] = tsc[l * 2];  p_ts[1] = tsc[l * 2 + 1];
    }
    __syncthreads();  // B0 — the only barrier

    // ================= build X into wave-private LDS slice =================
    #pragma unroll
    for (int nt = 0; nt < 2; ++nt) {
        int r  = nt * 16 + lo;                  // row within wave slice
        int bl = (w * 32 + r) >> 3;
        int bg = grp * 16 + bl;
        unsigned int m32 = msk[w * 32 + r];
        unsigned int mq  = (m32 >> (hi * 8)) & 0xffu;
        const float4* zp = (const float4*)(z_sample + bg * 32 + hi * 8);
        float4 za = zp[0], zb = zp[1];
        uint4 f0;   // masked z
        f0.x = pk2((mq & 1u)   ? za.x : 0.f, (mq & 2u)   ? za.y : 0.f);
        f0.y = pk2((mq & 4u)   ? za.z : 0.f, (mq & 8u)   ? za.w : 0.f);
        f0.z = pk2((mq & 16u)  ? zb.x : 0.f, (mq & 32u)  ? zb.y : 0.f);
        f0.w = pk2((mq & 64u)  ? zb.z : 0.f, (mq & 128u) ? zb.w : 0.f);
        uint4 f1;   // mask indicator bf16 1.0
        f1.x = ((mq & 1u)   ? 0x3F80u : 0u) | ((mq & 2u)   ? 0x3F800000u : 0u);
        f1.y = ((mq & 4u)   ? 0x3F80u : 0u) | ((mq & 8u)   ? 0x3F800000u : 0u);
        f1.z = ((mq & 16u)  ? 0x3F80u : 0u) | ((mq & 32u)  ? 0x3F800000u : 0u);
        f1.w = ((mq & 64u)  ? 0x3F80u : 0u) | ((mq & 128u) ? 0x3F800000u : 0u);
        unsigned int cb8 = cvl[bl];
        int lam = cb8 & 7, tf = (cb8 >> 3) & 1;
        int zsb = (hi == 0) ? 24 : (hi - 1) * 8;
        const float4* sp = (const float4*)(z_shared + bg * 32 + zsb);
        float4 sa = sp[0], sb = sp[1];
        uint4 fz;
        fz.x = pk2(sa.x, sa.y); fz.y = pk2(sa.z, sa.w);
        fz.z = pk2(sb.x, sb.y); fz.w = pk2(sb.z, sb.w);
        unsigned int ohw = tf ? (0x3F80u << ((lam & 1) << 4)) : 0u;
        int lq = lam >> 1;
        uint4 fo;
        fo.x = (lq == 0) ? ohw : 0u;
        fo.y = (lq == 1) ? ohw : 0u;
        fo.z = (lq == 2) ? ohw : 0u;
        fo.w = (lq == 3) ? ohw : 0u;
        bool h0 = (hi == 0);
        uint4 f2, f3;
        f2.x = h0 ? fo.x : fz.x;  f2.y = h0 ? fo.y : fz.y;
        f2.z = h0 ? fo.z : fz.z;  f2.w = h0 ? fo.w : fz.w;
        f3.x = h0 ? fz.x : 0u;    f3.y = h0 ? fz.y : 0u;
        f3.z = h0 ? fz.z : 0u;    f3.w = h0 ? fz.w : 0u;
        *(uint4*)&XH[w][r][hi * 8]      = f0;
        *(uint4*)&XH[w][r][32 + hi * 8] = f1;
        *(uint4*)&XH[w][r][64 + hi * 8] = f2;
        *(uint4*)&XH[w][r][96 + hi * 8] = f3;
    }
    // (in-wave LDS RAW ordered by lgkmcnt — no barrier)

    const float inv128 = 1.0f / 128.0f;
    const unsigned short* w1p = wscr + (size_t)(l * 32) * 512 + lane * 8;
    const unsigned short* w2p = wscr + (size_t)((32 + l) * 32) * 512 + lane * 8;

    // ================= GEMM1: 2-frag lookahead weight stream =================
    f32x4 acc[8][2];
    #pragma unroll
    for (int cb = 0; cb < 8; ++cb)
        #pragma unroll
        for (int nt = 0; nt < 2; ++nt) acc[cb][nt] = (f32x4){0.f, 0.f, 0.f, 0.f};
    {
        bf16x8 wfA[2], wfB[2];
        wfA[0] = ld_frag(w1p + 0 * 512);        // (cb0,ks0)
        wfA[1] = ld_frag(w1p + 4 * 512);        // (cb1,ks0)
        #pragma unroll
        for (int ks = 0; ks < 4; ++ks) {
            bf16x8 bf0 = ld_frag(&XH[w][lo][ks * 32 + hi * 8]);
            bf16x8 bf1 = ld_frag(&XH[w][16 + lo][ks * 32 + hi * 8]);
            #pragma unroll
            for (int p = 0; p < 4; ++p) {
                // prefetch next pair
                int ncb = (p < 3) ? (2 * p + 2) : 0;
                int nks = (p < 3) ? ks : ks + 1;
                if (p < 3 || ks < 3) {
                    wfB[0] = ld_frag(w1p + (ncb * 4 + nks) * 512);
                    wfB[1] = ld_frag(w1p + ((ncb + 1) * 4 + nks) * 512);
                }
                int cb = 2 * p;
                acc[cb][0]     = __builtin_amdgcn_mfma_f32_16x16x32_bf16(wfA[0], bf0, acc[cb][0], 0, 0, 0);
                acc[cb][1]     = __builtin_amdgcn_mfma_f32_16x16x32_bf16(wfA[0], bf1, acc[cb][1], 0, 0, 0);
                acc[cb + 1][0] = __builtin_amdgcn_mfma_f32_16x16x32_bf16(wfA[1], bf0, acc[cb + 1][0], 0, 0, 0);
                acc[cb + 1][1] = __builtin_amdgcn_mfma_f32_16x16x32_bf16(wfA[1], bf1, acc[cb + 1][1], 0, 0, 0);
                wfA[0] = wfB[0];  wfA[1] = wfB[1];
            }
        }
    }

    // ---- GN1 stats in-wave ----
    float s1[2] = {0.f, 0.f}, s2[2] = {0.f, 0.f};
    #pragma unroll
    for (int cb = 0; cb < 8; ++cb) {
        float4 b4 = *(const float4*)&p_b1[cb * 16 + hi * 4];
        #pragma unroll
        for (int rg = 0; rg < 4; ++rg) {
            float bias = ((const float*)&b4)[rg];
            #pragma unroll
            for (int nt = 0; nt < 2; ++nt) {
                float v = acc[cb][nt][rg] + bias;
                acc[cb][nt][rg] = v;
                s1[nt] += v;  s2[nt] += v * v;
            }
        }
    }
    float rstd[2], nrm_off[2];   // nrm_off = -mu*rstd  (norm = fma(v, rstd, off))
    #pragma unroll
    for (int nt = 0; nt < 2; ++nt) {
        s1[nt] += __shfl_xor(s1[nt], 16, 64);  s1[nt] += __shfl_xor(s1[nt], 32, 64);
        s2[nt] += __shfl_xor(s2[nt], 16, 64);  s2[nt] += __shfl_xor(s2[nt], 32, 64);
        float m_  = s1[nt] * inv128;
        float var = s2[nt] * inv128 - m_ * m_;
        float r   = rsqrtf(var + 1e-5f);
        rstd[nt] = r;  nrm_off[nt] = -m_ * r;
    }
    // ---- normalize + SiLU -> overwrite X slice with H ----
    #pragma unroll
    for (int cb = 0; cb < 8; ++cb) {
        float4 gw4 = *(const float4*)&p_g1w[cb * 16 + hi * 4];
        float4 gb4 = *(const float4*)&p_g1b[cb * 16 + hi * 4];
        #pragma unroll
        for (int nt = 0; nt < 2; ++nt) {
            float sl[4];
            #pragma unroll
            for (int rg = 0; rg < 4; ++rg) {
                float tn = acc[cb][nt][rg] * rstd[nt] + nrm_off[nt];   // 1 fma + 1 mul... (2 ops)
                float x  = tn * ((const float*)&gw4)[rg] + ((const float*)&gb4)[rg];
                sl[rg] = siluf(x);
            }
            *(uint2*)&XH[w][nt * 16 + lo][cb * 16 + hi * 4] =
                make_uint2(pk2(sl[0], sl[1]), pk2(sl[2], sl[3]));
        }
    }

    // ================= GEMM2: 2-frag lookahead weight stream =================
    #pragma unroll
    for (int cb = 0; cb < 8; ++cb)
        #pragma unroll
        for (int nt = 0; nt < 2; ++nt) acc[cb][nt] = (f32x4){0.f, 0.f, 0.f, 0.f};
    {
        bf16x8 wfA[2], wfB[2];
        wfA[0] = ld_frag(w2p + 0 * 512);
        wfA[1] = ld_frag(w2p + 4 * 512);
        #pragma unroll
        for (int ks = 0; ks < 4; ++ks) {
            bf16x8 bf0 = ld_frag(&XH[w][lo][ks * 32 + hi * 8]);
            bf16x8 bf1 = ld_frag(&XH[w][16 + lo][ks * 32 + hi * 8]);
            #pragma unroll
            for (int p = 0; p < 4; ++p) {
                int ncb = (p < 3) ? (2 * p + 2) : 0;
                int nks = (p < 3) ? ks : ks + 1;
                if (p < 3 || ks < 3) {
                    wfB[0] = ld_frag(w2p + (ncb * 4 + nks) * 512);
                    wfB[1] = ld_frag(w2p + ((ncb + 1) * 4 + nks) * 512);
                }
                int cb = 2 * p;
                acc[cb][0]     = __builtin_amdgcn_mfma_f32_16x16x32_bf16(wfA[0], bf0, acc[cb][0], 0, 0, 0);
                acc[cb][1]     = __builtin_amdgcn_mfma_f32_16x16x32_bf16(wfA[0], bf1, acc[cb][1], 0, 0, 0);
                acc[cb + 1][0] = __builtin_amdgcn_mfma_f32_16x16x32_bf16(wfA[1], bf0, acc[cb + 1][0], 0, 0, 0);
                acc[cb + 1][1] = __builtin_amdgcn_mfma_f32_16x16x32_bf16(wfA[1], bf1, acc[cb + 1][1], 0, 0, 0);
                wfA[0] = wfB[0];  wfA[1] = wfB[1];
            }
        }
    }

    // ---- GN2 stats in-wave ----
    float t1[2] = {0.f, 0.f}, t2[2] = {0.f, 0.f};
    #pragma unroll
    for (int cb = 0; cb < 8; ++cb) {
        float4 b4 = *(const float4*)&p_b2[cb * 16 + hi * 4];
        #pragma unroll
        for (int rg = 0; rg < 4; ++rg) {
            float bias = ((const float*)&b4)[rg];
            #pragma unroll
            for (int nt = 0; nt < 2; ++nt) {
                float v = acc[cb][nt][rg] + bias;
                acc[cb][nt][rg] = v;
                t1[nt] += v;  t2[nt] += v * v;
            }
        }
    }
    float rstd2[2], off2[2];
    #pragma unroll
    for (int nt = 0; nt < 2; ++nt) {
        t1[nt] += __shfl_xor(t1[nt], 16, 64);  t1[nt] += __shfl_xor(t1[nt], 32, 64);
        t2[nt] += __shfl_xor(t2[nt], 16, 64);  t2[nt] += __shfl_xor(t2[nt], 32, 64);
        float m_  = t1[nt] * inv128;
        float var = t2[nt] * inv128 - m_ * m_;
        float r   = rsqrtf(var + 1e-5f);
        rstd2[nt] = r;  off2[nt] = -m_ * r;
    }
    // ---- normalize + SiLU + 128->2 dot, in-wave ----
    float pmp[2] = {0.f, 0.f}, plp[2] = {0.f, 0.f};
    #pragma unroll
    for (int cb = 0; cb < 8; ++cb) {
        float4 gw4 = *(const float4*)&p_g2w[cb * 16 + hi * 4];
        float4 gb4 = *(const float4*)&p_g2b[cb * 16 + hi * 4];
        float4 w04 = *(const float4*)&p_w3[0][cb * 16 + hi * 4];
        float4 w14 = *(const float4*)&p_w3[1][cb * 16 + hi * 4];
        #pragma unroll
        for (int rg = 0; rg < 4; ++rg) {
            float wg = ((const float*)&gw4)[rg], gb = ((const float*)&gb4)[rg];
            float w0 = ((const float*)&w04)[rg], w1 = ((const float*)&w14)[rg];
            #pragma unroll
            for (int nt = 0; nt < 2; ++nt) {
                float tn = acc[cb][nt][rg] * rstd2[nt] + off2[nt];
                float x  = tn * wg + gb;
                float sl = siluf(x);
                pmp[nt] += sl * w0;
                plp[nt] += sl * w1;
            }
        }
    }
    #pragma unroll
    for (int nt = 0; nt < 2; ++nt) {
        pmp[nt] += __shfl_xor(pmp[nt], 16, 64);  pmp[nt] += __shfl_xor(pmp[nt], 32, 64);
        plp[nt] += __shfl_xor(plp[nt], 16, 64);  plp[nt] += __shfl_xor(plp[nt], 32, 64);
    }

    // ---- tanh-scale + KLD + mean over g + accumulate ----
    {
        float sc0 = __expf(p_ts[0]), sc1 = __expf(p_ts[1]);
        float is0 = __expf(-p_ts[0]), is1 = __expf(-p_ts[1]);
        #pragma unroll
        for (int nt = 0; nt < 2; ++nt) {
            float pm = pmp[nt] + p_b3[0];
            float pl = plp[nt] + p_b3[1];
            float e0 = __expf(2.0f * pm * is0);
            pm = (1.0f - 2.0f * __fdividef(1.0f, e0 + 1.0f)) * sc0;
            float e1 = __expf(2.0f * pl * is1);
            pl = (1.0f - 2.0f * __fdividef(1.0f, e1 + 1.0f)) * sc1;
            int r  = w * 32 + nt * 16 + lo;
            int bg = grp * 16 + (r >> 3);
            float zm = z_mean[bg * 32 + l];
            float zl = z_logstd[bg * 32 + l];
            float vq = __expf(2.0f * zl);
            float d  = zm - pm;
            float kld = pl - zl + (vq + d * d) * 0.5f * __expf(-2.0f * pl) - 0.5f;
            kld += __shfl_xor(kld, 1, 64);
            kld += __shfl_xor(kld, 2, 64);
            kld += __shfl_xor(kld, 4, 64);
            if (hi == 0 && (lo & 7) == 0) atomicAdd(&out[bg], kld * 0.125f);
        }
    }
}

extern "C" void kernel_launch(void* const* d_in, const int* in_sizes, int n_in,
                              void* d_out, int out_size, void* d_ws, size_t ws_size,
                              hipStream_t stream) {
    const float* z_sample      = (const float*)d_in[0];
    const int*   target        = (const int*)d_in[1];
    const float* z_mean        = (const float*)d_in[2];
    const float* z_logstd      = (const float*)d_in[3];
    const float* z_shared      = (const float*)d_in[4];
    const float* u_gumbel      = (const float*)d_in[5];
    const float* u_adj         = (const float*)d_in[6];
    const float* target_params = (const float*)d_in[7];
    const float* enco_theta    = (const float*)d_in[8];
    const float* enco_gamma    = (const float*)d_in[9];
    const float* W1            = (const float*)d_in[10];
    const float* pb1           = (const float*)d_in[11];
    const float* g1w           = (const float*)d_in[12];
    const float* g1b           = (const float*)d_in[13];
    const float* W2            = (const float*)d_in[14];
    const float* pb2           = (const float*)d_in[15];
    const float* g2w           = (const float*)d_in[16];
    const float* g2b           = (const float*)d_in[17];
    const float* W3            = (const float*)d_in[18];
    const float* pb3           = (const float*)d_in[19];
    const float* tsc           = (const float*)d_in[20];

    unsigned char* cvarpk = (unsigned char*)d_ws;                          // 32 KB
    unsigned int*  wsmask = (unsigned int*)((char*)d_ws + 32768);          // 1 MB
    unsigned short* wscr  = (unsigned short*)((char*)d_ws + 32768 + 1048576); // 2 MB

    prep_kernel<<<1536, 256, 0, stream>>>(u_gumbel, u_adj, target_params,
                                          enco_theta, enco_gamma, target,
                                          W1, W2, (float*)d_out,
                                          cvarpk, wsmask, wscr);
    fused_kernel<<<2048, 256, 0, stream>>>(z_sample, z_mean, z_logstd, z_shared,
                                           pb1, g1w, g1b, pb2, g2w, g2b,
                                           W3, pb3, tsc, wscr, cvarpk, wsmask,
                                           (float*)d_out);
}